// Round 1
// baseline (881.779 us; speedup 1.0000x reference)
//
#include <hip/hip_runtime.h>
#include <math.h>
#include <stdint.h>

// ---------------------------------------------------------------------------
// TemporalRelationGraph forward, MI355X
// Shapes: B=256, SEQ=8, NOBJ=10, SD=256, K=3, D=1024, NB=512, NC=174
// Pipeline:
//   var_kernel : per-b Gram S=flat flat^T, power iteration for sigma_max of
//                the 3 center-difference matrices, softmax weights, writes
//                relu(new_input) (2048 x 1024)
//   p_gemm     : per scale s, P_{s,j} = R @ W1_s[j*1024:(j+1)*1024]  (f32 tiled)
//   hsum_kernel: Hsum[row][si*512+c] = sum_rows relu(b1 + sum_j P[rel_j])
//   out_gemm   : out = Hsum(2048x2048) @ vstack(w2_4..w2_1) + counted biases
// Plan tables are compile-time (train/test plans are provably identical).
// ---------------------------------------------------------------------------

#define PITER 20

__device__ const int8_t ROWS4[12][5] = {
  {3, 0,1,2,3},
  {4, 0,1,2,3},{4, 1,2,3,4},
  {5, 0,1,2,3},{5, 1,2,3,4},{5, 2,3,4,5},
  {6, 0,1,2,3},{6, 1,2,3,4},{6, 2,3,4,5},{6, 3,4,5,6},
  {7, 0,2,4,6},{7, 1,3,5,7},
};
__device__ const int8_t ROWS3[15][4] = {
  {2, 0,1,2},
  {3, 0,1,2},{3, 1,2,3},
  {4, 0,1,2},{4, 1,2,3},{4, 2,3,4},
  {5, 0,2,4},{5, 1,3,5},
  {6, 0,2,4},{6, 1,3,5},{6, 2,4,6},
  {7, 0,2,4},{7, 1,3,5},{7, 2,4,6},{7, 3,5,7},
};
__device__ const int8_t ROWS2[19][3] = {
  {1, 0,1},
  {2, 0,1},{2, 1,2},
  {3, 0,2},{3, 1,3},
  {4, 0,2},{4, 1,3},{4, 2,4},
  {5, 0,3},{5, 1,4},{5, 2,5},
  {6, 0,3},{6, 1,4},{6, 2,5},{6, 3,6},
  {7, 0,4},{7, 1,5},{7, 2,6},{7, 3,7},
};
__device__ const int8_t ROWS1[36][2] = {
  {0,0},
  {1,0},{1,1},
  {2,0},{2,1},{2,2},
  {3,0},{3,1},{3,2},{3,3},
  {4,0},{4,1},{4,2},{4,3},{4,4},
  {5,0},{5,1},{5,2},{5,3},{5,4},{5,5},
  {6,0},{6,1},{6,2},{6,3},{6,4},{6,5},{6,6},
  {7,0},{7,1},{7,2},{7,3},{7,4},{7,5},{7,6},{7,7},
};
// row counts per (t, scale-index): si 0->s4, 1->s3, 2->s2, 3->s1
__device__ const float CNT[8][4] = {
  {0,0,0,1},{0,0,1,2},{0,1,2,3},{1,2,2,4},
  {2,3,3,5},{3,2,3,6},{4,3,4,7},{2,4,4,8},
};

// ---------------------------------------------------------------------------
__global__ __launch_bounds__(256) void var_kernel(
    const float* __restrict__ init, const float* __restrict__ graph,
    float* __restrict__ Rbuf)
{
  __shared__ float sch[80][65];   // 64-wide d-chunk of flat[b], padded
  __shared__ float S[80][81];     // Gram flat flat^T
  __shared__ float vv[80];
  __shared__ float uu[80];
  __shared__ float red[2];
  __shared__ float lamS[3];
  __shared__ float wk[3];

  const int b = blockIdx.x;
  const int tid = threadIdx.x;
  const float* fb = init + (size_t)b * 80 * 256;

  // ---- S = flat @ flat^T, accumulated over 4 chunks of 64 dims ----
  float acc[25];
#pragma unroll
  for (int q = 0; q < 25; ++q) acc[q] = 0.f;

  for (int ch = 0; ch < 4; ++ch) {
    __syncthreads();
#pragma unroll
    for (int c = 0; c < 20; ++c) {
      int idx = c * 256 + tid;          // 0..5119
      int r = idx >> 6, dc = idx & 63;
      sch[r][dc] = fb[(size_t)r * 256 + ch * 64 + dc];
    }
    __syncthreads();
    for (int q = 0; q < 25; ++q) {
      int e = tid * 25 + q;             // 0..6399
      int i = e / 80, j = e - i * 80;
      float s_ = 0.f;
#pragma unroll 16
      for (int dd = 0; dd < 64; ++dd) s_ += sch[i][dd] * sch[j][dd];
      acc[q] += s_;
    }
  }
  __syncthreads();
  for (int q = 0; q < 25; ++q) {
    int e = tid * 25 + q;
    int i = e / 80, j = e - i * 80;
    S[i][j] = acc[q];
  }
  __syncthreads();

  // ---- power iteration on G_k = S - s_k 1^T - 1 s_k^T + S_kk 11^T ----
  for (int k = 0; k < 3; ++k) {
    if (tid < 80) vv[tid] = 1.0f;
    __syncthreads();
    for (int it = 0; it < PITER; ++it) {
      if (tid < 80) {
        float sv = 0.f, skv = 0.f;
        for (int j = 0; j < 80; ++j) { float vj = vv[j]; sv += vj; skv += S[k][j] * vj; }
        float ui = 0.f;
        for (int j = 0; j < 80; ++j) ui += S[tid][j] * vv[j];
        ui += (S[k][k] - 0.f) * sv - S[tid][k] * sv - skv;
        uu[tid] = ui;
      }
      __syncthreads();
      if (tid == 0) {
        float n2 = 0.f, rr = 0.f;
        for (int j = 0; j < 80; ++j) { n2 += uu[j] * uu[j]; rr += uu[j] * vv[j]; }
        red[0] = rsqrtf(n2);
        red[1] = rr;                    // Rayleigh quotient (v was unit)
        if (it == PITER - 1) lamS[k] = rr;
      }
      __syncthreads();
      if (tid < 80) vv[tid] = uu[tid] * red[0];
      __syncthreads();
    }
  }
  if (tid == 0) {
    float L0 = -0.1f * lamS[0], L1 = -0.1f * lamS[1], L2 = -0.1f * lamS[2];
    float m = fmaxf(L0, fmaxf(L1, L2));
    float e0 = expf(L0 - m), e1 = expf(L1 - m), e2 = expf(L2 - m);
    float inv = 1.0f / (e0 + e1 + e2);
    wk[0] = e0 * inv; wk[1] = e1 * inv; wk[2] = e2 * inv;
  }
  __syncthreads();

  // ---- write relu(new_input): var (k=0..2) then graph_out ----
  const int d = tid;                    // 256 threads == SD
  const float c0 = fb[0 * 256 + d], c1 = fb[1 * 256 + d], c2 = fb[2 * 256 + d];
  const float w0 = wk[0], w1 = wk[1], w2 = wk[2];
  for (int t = 0; t < 8; ++t) {
    float xs = 0.f;
#pragma unroll
    for (int o = 0; o < 10; ++o) xs += fb[(size_t)(t * 10 + o) * 256 + d];
    size_t rb = ((size_t)(b * 8 + t)) * 1024;
    Rbuf[rb + 0 * 256 + d] = fmaxf(w0 * (xs - 10.f * c0), 0.f);
    Rbuf[rb + 1 * 256 + d] = fmaxf(w1 * (xs - 10.f * c1), 0.f);
    Rbuf[rb + 2 * 256 + d] = fmaxf(w2 * (xs - 10.f * c2), 0.f);
    float go = graph[((size_t)(b * 8 + t)) * 256 + d];
    Rbuf[rb + 768 + d] = fmaxf(go, 0.f);
  }
}

// ---------------------------------------------------------------------------
// P_{s,j} = Rbuf(2048x1024) @ W1_s[j*1024:(j+1)*1024, :512]
// grid: (512/64, 2048/64, s); 64x64 tile, BK=16, 4x4 per thread, f32.
__global__ __launch_bounds__(256) void p_gemm(
    const float* __restrict__ A, const float* __restrict__ W1,
    float* __restrict__ P, int s)
{
  __shared__ float As[64][17];
  __shared__ float Bs[16][65];
  const int tid = threadIdx.x;
  const int tx = tid & 15, ty = tid >> 4;
  const int colBase = blockIdx.x * 64;
  const int rowBase = blockIdx.y * 64;
  const int j = blockIdx.z;
  const float* Bp = W1 + (size_t)j * 1024 * 512;
  const int ldc = s * 512;

  float acc[4][4] = {{0.f}};

  for (int k0 = 0; k0 < 1024; k0 += 16) {
    {
      int r = tid >> 2, kq = (tid & 3) * 4;
      const float4 v = *(const float4*)(A + (size_t)(rowBase + r) * 1024 + k0 + kq);
      As[r][kq + 0] = v.x; As[r][kq + 1] = v.y; As[r][kq + 2] = v.z; As[r][kq + 3] = v.w;
    }
    {
      int kk = tid >> 4, cq = (tid & 15) * 4;
      const float4 v = *(const float4*)(Bp + (size_t)(k0 + kk) * 512 + colBase + cq);
      Bs[kk][cq + 0] = v.x; Bs[kk][cq + 1] = v.y; Bs[kk][cq + 2] = v.z; Bs[kk][cq + 3] = v.w;
    }
    __syncthreads();
#pragma unroll
    for (int kk = 0; kk < 16; ++kk) {
      float a0 = As[ty * 4 + 0][kk], a1 = As[ty * 4 + 1][kk];
      float a2 = As[ty * 4 + 2][kk], a3 = As[ty * 4 + 3][kk];
      float b0 = Bs[kk][tx * 4 + 0], b1 = Bs[kk][tx * 4 + 1];
      float b2 = Bs[kk][tx * 4 + 2], b3 = Bs[kk][tx * 4 + 3];
      acc[0][0] += a0 * b0; acc[0][1] += a0 * b1; acc[0][2] += a0 * b2; acc[0][3] += a0 * b3;
      acc[1][0] += a1 * b0; acc[1][1] += a1 * b1; acc[1][2] += a1 * b2; acc[1][3] += a1 * b3;
      acc[2][0] += a2 * b0; acc[2][1] += a2 * b1; acc[2][2] += a2 * b2; acc[2][3] += a2 * b3;
      acc[3][0] += a3 * b0; acc[3][1] += a3 * b1; acc[3][2] += a3 * b2; acc[3][3] += a3 * b3;
    }
    __syncthreads();
  }
#pragma unroll
  for (int i = 0; i < 4; ++i) {
    float* cp = P + (size_t)(rowBase + ty * 4 + i) * ldc + j * 512 + colBase + tx * 4;
#pragma unroll
    for (int jj = 0; jj < 4; ++jj) cp[jj] = acc[i][jj];
  }
}

// ---------------------------------------------------------------------------
// Hsum[row][si*512 + c] = sum over plan rows of relu(b1 + sum_j P[(b8+idx_j)][j*512+c])
__global__ __launch_bounds__(256) void hsum_kernel(
    const float* __restrict__ P, const float* __restrict__ b1,
    float* __restrict__ Hsum, int s, int si)
{
  const int row = blockIdx.x;       // b*8 + t
  const int t = row & 7;
  const int base = row - t;
  const int tid = threadIdx.x;
  const int ldp = s * 512;
  const int c0 = tid, c1 = tid + 256;
  const float bb0 = b1[c0], bb1 = b1[c1];
  float a0 = 0.f, a1 = 0.f;

  if (s == 4) {
    for (int r = 0; r < 12; ++r) {
      if (ROWS4[r][0] != t) continue;
      float h0 = bb0, h1 = bb1;
#pragma unroll
      for (int jj = 0; jj < 4; ++jj) {
        const float* p = P + (size_t)(base + ROWS4[r][1 + jj]) * ldp + jj * 512;
        h0 += p[c0]; h1 += p[c1];
      }
      a0 += fmaxf(h0, 0.f); a1 += fmaxf(h1, 0.f);
    }
  } else if (s == 3) {
    for (int r = 0; r < 15; ++r) {
      if (ROWS3[r][0] != t) continue;
      float h0 = bb0, h1 = bb1;
#pragma unroll
      for (int jj = 0; jj < 3; ++jj) {
        const float* p = P + (size_t)(base + ROWS3[r][1 + jj]) * ldp + jj * 512;
        h0 += p[c0]; h1 += p[c1];
      }
      a0 += fmaxf(h0, 0.f); a1 += fmaxf(h1, 0.f);
    }
  } else if (s == 2) {
    for (int r = 0; r < 19; ++r) {
      if (ROWS2[r][0] != t) continue;
      float h0 = bb0, h1 = bb1;
#pragma unroll
      for (int jj = 0; jj < 2; ++jj) {
        const float* p = P + (size_t)(base + ROWS2[r][1 + jj]) * ldp + jj * 512;
        h0 += p[c0]; h1 += p[c1];
      }
      a0 += fmaxf(h0, 0.f); a1 += fmaxf(h1, 0.f);
    }
  } else {
    for (int r = 0; r < 36; ++r) {
      if (ROWS1[r][0] != t) continue;
      const float* p = P + (size_t)(base + ROWS1[r][1]) * ldp;
      a0 += fmaxf(bb0 + p[c0], 0.f); a1 += fmaxf(bb1 + p[c1], 0.f);
    }
  }
  Hsum[(size_t)row * 2048 + si * 512 + c0] = a0;
  Hsum[(size_t)row * 2048 + si * 512 + c1] = a1;
}

// ---------------------------------------------------------------------------
// out(2048x174) = Hsum(2048x2048) @ vstack(w2_4,w2_3,w2_2,w2_1) + counted biases
__global__ __launch_bounds__(256) void out_gemm(
    const float* __restrict__ Hsum,
    const float* __restrict__ w2a, const float* __restrict__ w2b,
    const float* __restrict__ w2c, const float* __restrict__ w2d,
    const float* __restrict__ b2a, const float* __restrict__ b2b,
    const float* __restrict__ b2c, const float* __restrict__ b2d,
    float* __restrict__ out)
{
  __shared__ float As[64][17];
  __shared__ float Bs[16][65];
  const int tid = threadIdx.x;
  const int tx = tid & 15, ty = tid >> 4;
  const int colBase = blockIdx.x * 64;
  const int rowBase = blockIdx.y * 64;

  float acc[4][4] = {{0.f}};

  for (int k0 = 0; k0 < 2048; k0 += 16) {
    {
      int r = tid >> 2, kq = (tid & 3) * 4;
      const float4 v = *(const float4*)(Hsum + (size_t)(rowBase + r) * 2048 + k0 + kq);
      As[r][kq + 0] = v.x; As[r][kq + 1] = v.y; As[r][kq + 2] = v.z; As[r][kq + 3] = v.w;
    }
    {
      int kk = tid >> 4;
      int kg = k0 + kk;
      int sidx = kg >> 9;
      const float* w2p = (sidx == 0) ? w2a : (sidx == 1) ? w2b : (sidx == 2) ? w2c : w2d;
      int krow = kg & 511;
      int cq = (tid & 15) * 4;
#pragma unroll
      for (int q = 0; q < 4; ++q) {
        int col = colBase + cq + q;
        Bs[kk][cq + q] = (col < 174) ? w2p[(size_t)krow * 174 + col] : 0.f;
      }
    }
    __syncthreads();
#pragma unroll
    for (int kk = 0; kk < 16; ++kk) {
      float a0 = As[ty * 4 + 0][kk], a1 = As[ty * 4 + 1][kk];
      float a2 = As[ty * 4 + 2][kk], a3 = As[ty * 4 + 3][kk];
      float b0 = Bs[kk][tx * 4 + 0], b1 = Bs[kk][tx * 4 + 1];
      float b2 = Bs[kk][tx * 4 + 2], b3 = Bs[kk][tx * 4 + 3];
      acc[0][0] += a0 * b0; acc[0][1] += a0 * b1; acc[0][2] += a0 * b2; acc[0][3] += a0 * b3;
      acc[1][0] += a1 * b0; acc[1][1] += a1 * b1; acc[1][2] += a1 * b2; acc[1][3] += a1 * b3;
      acc[2][0] += a2 * b0; acc[2][1] += a2 * b1; acc[2][2] += a2 * b2; acc[2][3] += a2 * b3;
      acc[3][0] += a3 * b0; acc[3][1] += a3 * b1; acc[3][2] += a3 * b2; acc[3][3] += a3 * b3;
    }
    __syncthreads();
  }
#pragma unroll
  for (int i = 0; i < 4; ++i) {
    int row = rowBase + ty * 4 + i;
    int tt = row & 7;
#pragma unroll
    for (int jj = 0; jj < 4; ++jj) {
      int col = colBase + tx * 4 + jj;
      if (col < 174) {
        float bias = CNT[tt][0] * b2a[col] + CNT[tt][1] * b2b[col]
                   + CNT[tt][2] * b2c[col] + CNT[tt][3] * b2d[col];
        out[(size_t)row * 174 + col] = acc[i][jj] + bias;
      }
    }
  }
}

// ---------------------------------------------------------------------------
extern "C" void kernel_launch(void* const* d_in, const int* in_sizes, int n_in,
                              void* d_out, int out_size, void* d_ws, size_t ws_size,
                              hipStream_t stream) {
  const float* graph = (const float*)d_in[0];
  const float* init  = (const float*)d_in[1];
  // d_in[2] is is_test: train/test plans are identical for SEQ=8,NF=4,SUB=10 -> ignored.
  const float* w1[4] = {(const float*)d_in[3],  (const float*)d_in[7],
                        (const float*)d_in[11], (const float*)d_in[15]};
  const float* b1[4] = {(const float*)d_in[4],  (const float*)d_in[8],
                        (const float*)d_in[12], (const float*)d_in[16]};
  const float* w2[4] = {(const float*)d_in[5],  (const float*)d_in[9],
                        (const float*)d_in[13], (const float*)d_in[17]};
  const float* b2[4] = {(const float*)d_in[6],  (const float*)d_in[10],
                        (const float*)d_in[14], (const float*)d_in[18]};
  float* out = (float*)d_out;

  char* ws = (char*)d_ws;
  float* Rbuf = (float*)ws;                               // 2048*1024*4 = 8 MiB
  float* Pbuf = (float*)(ws + (size_t)8  * 1024 * 1024);  // max 2048*2048*4 = 16 MiB
  float* Hsum = (float*)(ws + (size_t)24 * 1024 * 1024);  // 2048*2048*4 = 16 MiB

  var_kernel<<<256, 256, 0, stream>>>(init, graph, Rbuf);

  const int scales[4] = {4, 3, 2, 1};
  for (int si = 0; si < 4; ++si) {
    int s = scales[si];
    dim3 g(8, 32, s);
    p_gemm<<<g, 256, 0, stream>>>(Rbuf, w1[si], Pbuf, s);
    hsum_kernel<<<2048, 256, 0, stream>>>(Pbuf, b1[si], Hsum, s, si);
  }

  out_gemm<<<dim3(3, 32), 256, 0, stream>>>(Hsum, w2[0], w2[1], w2[2], w2[3],
                                            b2[0], b2[1], b2[2], b2[3], out);
}

// Round 2
// 281.800 us; speedup vs baseline: 3.1291x; 3.1291x over previous
//
#include <hip/hip_runtime.h>
#include <math.h>
#include <stdint.h>

// ---------------------------------------------------------------------------
// TemporalRelationGraph forward, MI355X — bf16 MFMA pipeline
// Shapes: B=256, SEQ=8, NOBJ=10, SD=256, K=3, D=1024, NB=512, NC=174
//   var_kernel : Gram + power-iter sigma_max + softmax -> Rbf = relu(new_input) bf16 (2048x1024)
//   w1t_kernel : W1 slices -> W1T bf16 [10 slices][512 col][1024 k]
//   w2t_kernel : W2 -> W2T bf16 [192 col(pad)][2048 k]
//   p_mfma     : P(2048x5120 bf16) = Rbf @ W1T^T   (16x16x32 bf16 MFMA, 128x128 tile)
//   hsum_all   : Hsum(2048x2048 bf16), windowed relu-sums per scale
//   out_mfma   : out(2048x174 f32) = Hsum @ W2T^T + counted biases
// Train/test plans identical for SEQ=8,NF=4,SUB=10 -> is_test ignored.
// ---------------------------------------------------------------------------

#define PITER 20

typedef __attribute__((ext_vector_type(8))) short short8v;
typedef __attribute__((ext_vector_type(4))) float f32x4;

__device__ __forceinline__ short f2bf(float f) {
  uint32_t u = __float_as_uint(f);
  u += 0x7fffu + ((u >> 16) & 1u);      // RNE
  return (short)(u >> 16);
}
__device__ __forceinline__ float bf2f(short s) {
  return __uint_as_float(((uint32_t)(uint16_t)s) << 16);
}
__device__ __forceinline__ void gload16(const void* g, void* l) {
  __builtin_amdgcn_global_load_lds(
      (const __attribute__((address_space(1))) void*)g,
      (__attribute__((address_space(3))) void*)l, 16, 0, 0);
}

__device__ const int8_t ROWS4[12][5] = {
  {3, 0,1,2,3},
  {4, 0,1,2,3},{4, 1,2,3,4},
  {5, 0,1,2,3},{5, 1,2,3,4},{5, 2,3,4,5},
  {6, 0,1,2,3},{6, 1,2,3,4},{6, 2,3,4,5},{6, 3,4,5,6},
  {7, 0,2,4,6},{7, 1,3,5,7},
};
__device__ const int8_t ROWS3[15][4] = {
  {2, 0,1,2},
  {3, 0,1,2},{3, 1,2,3},
  {4, 0,1,2},{4, 1,2,3},{4, 2,3,4},
  {5, 0,2,4},{5, 1,3,5},
  {6, 0,2,4},{6, 1,3,5},{6, 2,4,6},
  {7, 0,2,4},{7, 1,3,5},{7, 2,4,6},{7, 3,5,7},
};
__device__ const int8_t ROWS2[19][3] = {
  {1, 0,1},
  {2, 0,1},{2, 1,2},
  {3, 0,2},{3, 1,3},
  {4, 0,2},{4, 1,3},{4, 2,4},
  {5, 0,3},{5, 1,4},{5, 2,5},
  {6, 0,3},{6, 1,4},{6, 2,5},{6, 3,6},
  {7, 0,4},{7, 1,5},{7, 2,6},{7, 3,7},
};
__device__ const int8_t ROWS1[36][2] = {
  {0,0},
  {1,0},{1,1},
  {2,0},{2,1},{2,2},
  {3,0},{3,1},{3,2},{3,3},
  {4,0},{4,1},{4,2},{4,3},{4,4},
  {5,0},{5,1},{5,2},{5,3},{5,4},{5,5},
  {6,0},{6,1},{6,2},{6,3},{6,4},{6,5},{6,6},
  {7,0},{7,1},{7,2},{7,3},{7,4},{7,5},{7,6},{7,7},
};
// window counts per (t, scale-index): si 0->s4, 1->s3, 2->s2, 3->s1
__device__ const float CNT[8][4] = {
  {0,0,0,1},{0,0,1,2},{0,1,2,3},{1,2,2,4},
  {2,3,3,5},{3,2,3,6},{4,3,4,7},{2,4,4,8},
};

// ---------------------------------------------------------------------------
__global__ __launch_bounds__(256) void var_kernel(
    const float* __restrict__ init, const float* __restrict__ graph,
    short* __restrict__ Rbuf)
{
  __shared__ float sch[80][65];
  __shared__ float S[80][81];
  __shared__ float vv[80];
  __shared__ float uu[80];
  __shared__ float red[2];
  __shared__ float lamS[3];
  __shared__ float wk[3];

  const int b = blockIdx.x;
  const int tid = threadIdx.x;
  const float* fb = init + (size_t)b * 80 * 256;

  float acc[25];
#pragma unroll
  for (int q = 0; q < 25; ++q) acc[q] = 0.f;

  for (int ch = 0; ch < 4; ++ch) {
    __syncthreads();
#pragma unroll
    for (int c = 0; c < 20; ++c) {
      int idx = c * 256 + tid;
      int r = idx >> 6, dc = idx & 63;
      sch[r][dc] = fb[(size_t)r * 256 + ch * 64 + dc];
    }
    __syncthreads();
    for (int q = 0; q < 25; ++q) {
      int e = tid * 25 + q;
      int i = e / 80, j = e - i * 80;
      float s_ = 0.f;
#pragma unroll 16
      for (int dd = 0; dd < 64; ++dd) s_ += sch[i][dd] * sch[j][dd];
      acc[q] += s_;
    }
  }
  __syncthreads();
  for (int q = 0; q < 25; ++q) {
    int e = tid * 25 + q;
    int i = e / 80, j = e - i * 80;
    S[i][j] = acc[q];
  }
  __syncthreads();

  for (int k = 0; k < 3; ++k) {
    if (tid < 80) vv[tid] = 1.0f;
    __syncthreads();
    for (int it = 0; it < PITER; ++it) {
      if (tid < 80) {
        float sv = 0.f, skv = 0.f;
        for (int j = 0; j < 80; ++j) { float vj = vv[j]; sv += vj; skv += S[k][j] * vj; }
        float ui = 0.f;
        for (int j = 0; j < 80; ++j) ui += S[tid][j] * vv[j];
        ui += S[k][k] * sv - S[tid][k] * sv - skv;
        uu[tid] = ui;
      }
      __syncthreads();
      if (tid == 0) {
        float n2 = 0.f, rr = 0.f;
        for (int j = 0; j < 80; ++j) { n2 += uu[j] * uu[j]; rr += uu[j] * vv[j]; }
        red[0] = rsqrtf(n2);
        if (it == PITER - 1) lamS[k] = rr;
      }
      __syncthreads();
      if (tid < 80) vv[tid] = uu[tid] * red[0];
      __syncthreads();
    }
  }
  if (tid == 0) {
    float L0 = -0.1f * lamS[0], L1 = -0.1f * lamS[1], L2 = -0.1f * lamS[2];
    float m = fmaxf(L0, fmaxf(L1, L2));
    float e0 = expf(L0 - m), e1 = expf(L1 - m), e2 = expf(L2 - m);
    float inv = 1.0f / (e0 + e1 + e2);
    wk[0] = e0 * inv; wk[1] = e1 * inv; wk[2] = e2 * inv;
  }
  __syncthreads();

  const int d = tid;
  const float c0 = fb[0 * 256 + d], c1 = fb[1 * 256 + d], c2 = fb[2 * 256 + d];
  const float w0 = wk[0], w1 = wk[1], w2 = wk[2];
  for (int t = 0; t < 8; ++t) {
    float xs = 0.f;
#pragma unroll
    for (int o = 0; o < 10; ++o) xs += fb[(size_t)(t * 10 + o) * 256 + d];
    size_t rb = ((size_t)(b * 8 + t)) * 1024;
    Rbuf[rb + 0 * 256 + d] = f2bf(fmaxf(w0 * (xs - 10.f * c0), 0.f));
    Rbuf[rb + 1 * 256 + d] = f2bf(fmaxf(w1 * (xs - 10.f * c1), 0.f));
    Rbuf[rb + 2 * 256 + d] = f2bf(fmaxf(w2 * (xs - 10.f * c2), 0.f));
    float go = graph[((size_t)(b * 8 + t)) * 256 + d];
    Rbuf[rb + 768 + d] = f2bf(fmaxf(go, 0.f));
  }
}

// ---------------------------------------------------------------------------
// Transpose one scale's W1 (s*1024 x 512 f32) into Out[j][col][k] bf16.
// grid: (k-tiles=32, col-tiles=16, j=s), 256 threads (32x8).
__global__ __launch_bounds__(256) void w1t_kernel(
    const float* __restrict__ W1, short* __restrict__ Out)
{
  __shared__ float sh[32][33];
  const int j = blockIdx.z;
  const int k0 = blockIdx.x * 32, c0 = blockIdx.y * 32;
  const int tx = threadIdx.x & 31, ty = threadIdx.x >> 5;
#pragma unroll
  for (int q = 0; q < 4; ++q) {
    int kk = ty + q * 8;
    sh[kk][tx] = W1[(size_t)(j * 1024 + k0 + kk) * 512 + c0 + tx];
  }
  __syncthreads();
#pragma unroll
  for (int q = 0; q < 4; ++q) {
    int cc = ty + q * 8;
    Out[(size_t)(j * 512 + c0 + cc) * 1024 + k0 + tx] = f2bf(sh[tx][cc]);
  }
}

// ---------------------------------------------------------------------------
// W2T[col][si*512+kr] = w2_si[kr][col], col padded to 192 with zeros.
__global__ __launch_bounds__(256) void w2t_kernel(
    const float* __restrict__ w2a, const float* __restrict__ w2b,
    const float* __restrict__ w2c, const float* __restrict__ w2d,
    short* __restrict__ O)
{
  int idx = blockIdx.x * 256 + threadIdx.x;      // < 192*2048
  int col = idx >> 11, kg = idx & 2047;
  int si = kg >> 9, kr = kg & 511;
  const float* w = (si == 0) ? w2a : (si == 1) ? w2b : (si == 2) ? w2c : w2d;
  O[idx] = (col < 174) ? f2bf(w[(size_t)kr * 174 + col]) : (short)0;
}

// ---------------------------------------------------------------------------
// P(2048 x 5120) bf16 = Rbf(2048x1024) @ W1T^T; 128x128 tile, BK=32, 4 waves.
__global__ __launch_bounds__(256) void p_mfma(
    const short* __restrict__ A, const short* __restrict__ W1T,
    short* __restrict__ P)
{
  __shared__ short As[128 * 32];
  __shared__ short Bs[128 * 32];
  const int tid = threadIdx.x, lane = tid & 63, w = tid >> 6;
  const int wr = w >> 1, wc = w & 1;
  const int rowBase = blockIdx.y * 128;
  const short* Bp = W1T + (size_t)blockIdx.x * 128 * 1024;
  const int rA = w * 16 + (lane >> 2);
  const int kkA = (lane & 3) * 8;

  f32x4 acc[4][4];
#pragma unroll
  for (int m = 0; m < 4; ++m)
#pragma unroll
    for (int n = 0; n < 4; ++n) acc[m][n] = (f32x4){0.f, 0.f, 0.f, 0.f};

  for (int k0 = 0; k0 < 1024; k0 += 32) {
    __syncthreads();
    gload16(A + (size_t)(rowBase + rA) * 1024 + k0 + kkA, As + w * 512);
    gload16(A + (size_t)(rowBase + 64 + rA) * 1024 + k0 + kkA, As + 2048 + w * 512);
    gload16(Bp + (size_t)rA * 1024 + k0 + kkA, Bs + w * 512);
    gload16(Bp + (size_t)(64 + rA) * 1024 + k0 + kkA, Bs + 2048 + w * 512);
    __syncthreads();
    short8v a[4], bv[4];
#pragma unroll
    for (int m = 0; m < 4; ++m)
      a[m] = *(const short8v*)(As + (wr * 64 + m * 16 + (lane & 15)) * 32 + (lane >> 4) * 8);
#pragma unroll
    for (int n = 0; n < 4; ++n)
      bv[n] = *(const short8v*)(Bs + (wc * 64 + n * 16 + (lane & 15)) * 32 + (lane >> 4) * 8);
#pragma unroll
    for (int m = 0; m < 4; ++m)
#pragma unroll
      for (int n = 0; n < 4; ++n)
        acc[m][n] = __builtin_amdgcn_mfma_f32_16x16x32_bf16(a[m], bv[n], acc[m][n], 0, 0, 0);
  }

  const int colG = blockIdx.x * 128 + wc * 64;
#pragma unroll
  for (int m = 0; m < 4; ++m) {
    int row = rowBase + wr * 64 + m * 16 + (lane >> 4) * 4;
#pragma unroll
    for (int n = 0; n < 4; ++n) {
      int col = colG + n * 16 + (lane & 15);
#pragma unroll
      for (int r = 0; r < 4; ++r)
        P[(size_t)(row + r) * 5120 + col] = f2bf(acc[m][n][r]);
    }
  }
}

// ---------------------------------------------------------------------------
// Hsum[row][si*512+c] bf16, all 4 scales in one kernel. P stride 5120.
__global__ __launch_bounds__(256) void hsum_all(
    const short* __restrict__ P,
    const float* __restrict__ b1a, const float* __restrict__ b1b,
    const float* __restrict__ b1c, const float* __restrict__ b1d,
    short* __restrict__ Hsum)
{
  const int row = blockIdx.x, t = row & 7, base = row - t;
  const int tid = threadIdx.x;
  const int c0 = tid, c1 = tid + 256;

  {  // si=0, s=4, cols 0..2047
    float bb0 = b1a[c0], bb1 = b1a[c1], a0 = 0.f, a1 = 0.f;
    for (int r = 0; r < 12; ++r) {
      if (ROWS4[r][0] != t) continue;
      float h0 = bb0, h1 = bb1;
#pragma unroll
      for (int jj = 0; jj < 4; ++jj) {
        const short* p = P + (size_t)(base + ROWS4[r][1 + jj]) * 5120 + jj * 512;
        h0 += bf2f(p[c0]); h1 += bf2f(p[c1]);
      }
      a0 += fmaxf(h0, 0.f); a1 += fmaxf(h1, 0.f);
    }
    Hsum[(size_t)row * 2048 + c0] = f2bf(a0);
    Hsum[(size_t)row * 2048 + c1] = f2bf(a1);
  }
  {  // si=1, s=3, cols 2048..3583
    float bb0 = b1b[c0], bb1 = b1b[c1], a0 = 0.f, a1 = 0.f;
    for (int r = 0; r < 15; ++r) {
      if (ROWS3[r][0] != t) continue;
      float h0 = bb0, h1 = bb1;
#pragma unroll
      for (int jj = 0; jj < 3; ++jj) {
        const short* p = P + (size_t)(base + ROWS3[r][1 + jj]) * 5120 + 2048 + jj * 512;
        h0 += bf2f(p[c0]); h1 += bf2f(p[c1]);
      }
      a0 += fmaxf(h0, 0.f); a1 += fmaxf(h1, 0.f);
    }
    Hsum[(size_t)row * 2048 + 512 + c0] = f2bf(a0);
    Hsum[(size_t)row * 2048 + 512 + c1] = f2bf(a1);
  }
  {  // si=2, s=2, cols 3584..4607
    float bb0 = b1c[c0], bb1 = b1c[c1], a0 = 0.f, a1 = 0.f;
    for (int r = 0; r < 19; ++r) {
      if (ROWS2[r][0] != t) continue;
      float h0 = bb0, h1 = bb1;
#pragma unroll
      for (int jj = 0; jj < 2; ++jj) {
        const short* p = P + (size_t)(base + ROWS2[r][1 + jj]) * 5120 + 3584 + jj * 512;
        h0 += bf2f(p[c0]); h1 += bf2f(p[c1]);
      }
      a0 += fmaxf(h0, 0.f); a1 += fmaxf(h1, 0.f);
    }
    Hsum[(size_t)row * 2048 + 1024 + c0] = f2bf(a0);
    Hsum[(size_t)row * 2048 + 1024 + c1] = f2bf(a1);
  }
  {  // si=3, s=1, cols 4608..5119
    float bb0 = b1d[c0], bb1 = b1d[c1], a0 = 0.f, a1 = 0.f;
    for (int r = 0; r < 36; ++r) {
      if (ROWS1[r][0] != t) continue;
      const short* p = P + (size_t)(base + ROWS1[r][1]) * 5120 + 4608;
      a0 += fmaxf(bb0 + bf2f(p[c0]), 0.f);
      a1 += fmaxf(bb1 + bf2f(p[c1]), 0.f);
    }
    Hsum[(size_t)row * 2048 + 1536 + c0] = f2bf(a0);
    Hsum[(size_t)row * 2048 + 1536 + c1] = f2bf(a1);
  }
}

// ---------------------------------------------------------------------------
// out(2048x174 f32) = Hsum(2048x2048) @ W2T^T + counted biases.
// 128x64 tile, BK=32; grid (3,16).
__global__ __launch_bounds__(256) void out_mfma(
    const short* __restrict__ H, const short* __restrict__ W2T,
    const float* __restrict__ b2a, const float* __restrict__ b2b,
    const float* __restrict__ b2c, const float* __restrict__ b2d,
    float* __restrict__ out)
{
  __shared__ short As[128 * 32];
  __shared__ short Bs[64 * 32];
  const int tid = threadIdx.x, lane = tid & 63, w = tid >> 6;
  const int wr = w >> 1, wc = w & 1;
  const int rowBase = blockIdx.y * 128, colBase = blockIdx.x * 64;
  const int rA = w * 16 + (lane >> 2);
  const int kkA = (lane & 3) * 8;

  f32x4 acc[4][2];
#pragma unroll
  for (int m = 0; m < 4; ++m)
#pragma unroll
    for (int n = 0; n < 2; ++n) acc[m][n] = (f32x4){0.f, 0.f, 0.f, 0.f};

  for (int k0 = 0; k0 < 2048; k0 += 32) {
    __syncthreads();
    gload16(H + (size_t)(rowBase + rA) * 2048 + k0 + kkA, As + w * 512);
    gload16(H + (size_t)(rowBase + 64 + rA) * 2048 + k0 + kkA, As + 2048 + w * 512);
    gload16(W2T + (size_t)(colBase + rA) * 2048 + k0 + kkA, Bs + w * 512);
    __syncthreads();
    short8v a[4], bv[2];
#pragma unroll
    for (int m = 0; m < 4; ++m)
      a[m] = *(const short8v*)(As + (wr * 64 + m * 16 + (lane & 15)) * 32 + (lane >> 4) * 8);
#pragma unroll
    for (int n = 0; n < 2; ++n)
      bv[n] = *(const short8v*)(Bs + (wc * 32 + n * 16 + (lane & 15)) * 32 + (lane >> 4) * 8);
#pragma unroll
    for (int m = 0; m < 4; ++m)
#pragma unroll
      for (int n = 0; n < 2; ++n)
        acc[m][n] = __builtin_amdgcn_mfma_f32_16x16x32_bf16(a[m], bv[n], acc[m][n], 0, 0, 0);
  }

#pragma unroll
  for (int n = 0; n < 2; ++n) {
    int col = colBase + wc * 32 + n * 16 + (lane & 15);
    if (col >= 174) continue;
    float ba = b2a[col], bb = b2b[col], bc = b2c[col], bd = b2d[col];
#pragma unroll
    for (int m = 0; m < 4; ++m) {
      int row0 = rowBase + wr * 64 + m * 16 + (lane >> 4) * 4;
#pragma unroll
      for (int r = 0; r < 4; ++r) {
        int row = row0 + r, tt = row & 7;
        float bias = CNT[tt][0] * ba + CNT[tt][1] * bb + CNT[tt][2] * bc + CNT[tt][3] * bd;
        out[(size_t)row * 174 + col] = acc[m][n][r] + bias;
      }
    }
  }
}

// ---------------------------------------------------------------------------
extern "C" void kernel_launch(void* const* d_in, const int* in_sizes, int n_in,
                              void* d_out, int out_size, void* d_ws, size_t ws_size,
                              hipStream_t stream) {
  const float* graph = (const float*)d_in[0];
  const float* init  = (const float*)d_in[1];
  const float* w1[4] = {(const float*)d_in[3],  (const float*)d_in[7],
                        (const float*)d_in[11], (const float*)d_in[15]};
  const float* b1[4] = {(const float*)d_in[4],  (const float*)d_in[8],
                        (const float*)d_in[12], (const float*)d_in[16]};
  const float* w2[4] = {(const float*)d_in[5],  (const float*)d_in[9],
                        (const float*)d_in[13], (const float*)d_in[17]};
  const float* b2[4] = {(const float*)d_in[6],  (const float*)d_in[10],
                        (const float*)d_in[14], (const float*)d_in[18]};
  float* out = (float*)d_out;

  char* ws = (char*)d_ws;
  short* Rbf  = (short*)(ws + 0);                    // 4 MiB (dead after p_mfma)
  short* W1T  = (short*)(ws + ((size_t)4  << 20));   // 10 MiB (dead after p_mfma)
  short* P    = (short*)(ws + ((size_t)14 << 20));   // 20 MiB
  short* W2T  = (short*)(ws + ((size_t)34 << 20));   // 0.75 MiB
  short* Hsum = (short*)(ws + 0);                    // 8 MiB (reuses Rbf/W1T head)

  var_kernel<<<256, 256, 0, stream>>>(init, graph, Rbf);

  const int sliceBase[4] = {0, 4, 7, 9};
  for (int si = 0; si < 4; ++si) {
    int s = 4 - si;
    dim3 g(32, 16, s);
    w1t_kernel<<<g, 256, 0, stream>>>(w1[si], W1T + (size_t)sliceBase[si] * 512 * 1024);
  }
  w2t_kernel<<<1536, 256, 0, stream>>>(w2[0], w2[1], w2[2], w2[3], W2T);

  p_mfma<<<dim3(40, 16), 256, 0, stream>>>(Rbf, W1T, P);

  hsum_all<<<2048, 256, 0, stream>>>(P, b1[0], b1[1], b1[2], b1[3], Hsum);

  out_mfma<<<dim3(3, 16), 256, 0, stream>>>(Hsum, W2T, b2[0], b2[1], b2[2], b2[3], out);
}

// Round 3
// 137.779 us; speedup vs baseline: 6.3999x; 2.0453x over previous
//
#include <hip/hip_runtime.h>
#include <math.h>
#include <stdint.h>

// ---------------------------------------------------------------------------
// TemporalRelationGraph forward, MI355X — bf16 MFMA pipeline
// Shapes: B=256, SEQ=8, NOBJ=10, SD=256, K=3, D=1024, NB=512, NC=174
//   var_kernel : Gram(reg-tiled) + explicit Atilde + scale-only power iter
//                -> Rbf = relu(new_input) bf16 (2048x1024)
//   w1t_kernel : W1 slices -> W1T bf16 [10 slices][512 col][1024 k]
//   w2t_kernel : W2 -> W2T bf16 [192 col(pad)][2048 k]
//   p_mfma     : P(2048x5120 bf16) = Rbf @ W1T^T   (16x16x32 bf16 MFMA, 128x128 tile)
//   hsum_all   : Hsum(2048x2048 bf16), windowed relu-sums per scale (short2 loads)
//   out_mfma   : out(2048x174 f32) = Hsum @ W2T^T + counted biases
// Train/test plans identical for SEQ=8,NF=4,SUB=10 -> is_test ignored.
// ---------------------------------------------------------------------------

#define PITER 10

typedef __attribute__((ext_vector_type(8))) short short8v;
typedef __attribute__((ext_vector_type(4))) float f32x4;

__device__ __forceinline__ short f2bf(float f) {
  uint32_t u = __float_as_uint(f);
  u += 0x7fffu + ((u >> 16) & 1u);      // RNE
  return (short)(u >> 16);
}
__device__ __forceinline__ float bf2f(short s) {
  return __uint_as_float(((uint32_t)(uint16_t)s) << 16);
}
__device__ __forceinline__ void gload16(const void* g, void* l) {
  __builtin_amdgcn_global_load_lds(
      (const __attribute__((address_space(1))) void*)g,
      (__attribute__((address_space(3))) void*)l, 16, 0, 0);
}

__device__ const int8_t ROWS4[12][5] = {
  {3, 0,1,2,3},
  {4, 0,1,2,3},{4, 1,2,3,4},
  {5, 0,1,2,3},{5, 1,2,3,4},{5, 2,3,4,5},
  {6, 0,1,2,3},{6, 1,2,3,4},{6, 2,3,4,5},{6, 3,4,5,6},
  {7, 0,2,4,6},{7, 1,3,5,7},
};
__device__ const int8_t ROWS3[15][4] = {
  {2, 0,1,2},
  {3, 0,1,2},{3, 1,2,3},
  {4, 0,1,2},{4, 1,2,3},{4, 2,3,4},
  {5, 0,2,4},{5, 1,3,5},
  {6, 0,2,4},{6, 1,3,5},{6, 2,4,6},
  {7, 0,2,4},{7, 1,3,5},{7, 2,4,6},{7, 3,5,7},
};
__device__ const int8_t ROWS2[19][3] = {
  {1, 0,1},
  {2, 0,1},{2, 1,2},
  {3, 0,2},{3, 1,3},
  {4, 0,2},{4, 1,3},{4, 2,4},
  {5, 0,3},{5, 1,4},{5, 2,5},
  {6, 0,3},{6, 1,4},{6, 2,5},{6, 3,6},
  {7, 0,4},{7, 1,5},{7, 2,6},{7, 3,7},
};
__device__ const int8_t ROWS1[36][2] = {
  {0,0},
  {1,0},{1,1},
  {2,0},{2,1},{2,2},
  {3,0},{3,1},{3,2},{3,3},
  {4,0},{4,1},{4,2},{4,3},{4,4},
  {5,0},{5,1},{5,2},{5,3},{5,4},{5,5},
  {6,0},{6,1},{6,2},{6,3},{6,4},{6,5},{6,6},
  {7,0},{7,1},{7,2},{7,3},{7,4},{7,5},{7,6},{7,7},
};
// window counts per (t, scale-index): si 0->s4, 1->s3, 2->s2, 3->s1
__device__ const float CNT[8][4] = {
  {0,0,0,1},{0,0,1,2},{0,1,2,3},{1,2,2,4},
  {2,3,3,5},{3,2,3,6},{4,3,4,7},{2,4,4,8},
};

// ---------------------------------------------------------------------------
// One block per batch b (256 blocks, 256 threads).
// LDS: S[80][81] (25.9KB) + big[20800] (83.2KB: flat[80][260] then Atil[3][80][82])
//      + vbuf (2KB) + red (1.9KB)  ~= 113 KB -> 1 block/CU (grid==CU count).
__global__ __launch_bounds__(256) void var_kernel(
    const float* __restrict__ init, const float* __restrict__ graph,
    short* __restrict__ Rbuf)
{
  __shared__ float S[80][81];
  __shared__ float big[20800];
  __shared__ float vbuf[2][3][84];
  __shared__ float redA[240];
  __shared__ float redB[240];
  __shared__ float wk[3];

  const int b = blockIdx.x;
  const int tid = threadIdx.x;
  const float* fb = init + (size_t)b * 80 * 256;

  // ---- stage flat[b] into LDS, stride 260 floats ----
#pragma unroll
  for (int it = 0; it < 20; ++it) {
    int q = it * 256 + tid;             // 5120 float4s
    int r = q >> 6, c4 = q & 63;
    float4 v = *(const float4*)(fb + (size_t)r * 256 + c4 * 4);
    *(float4*)&big[r * 260 + c4 * 4] = v;
  }
  __syncthreads();

  // ---- Gram S = flat flat^T, 5x5 register tile per thread ----
  {
    const int tx = tid & 15, ty = tid >> 4;
    const int i0 = ty * 5, j0 = tx * 5;
    float c[5][5];
#pragma unroll
    for (int r = 0; r < 5; ++r)
#pragma unroll
      for (int cc = 0; cc < 5; ++cc) c[r][cc] = 0.f;

    for (int dd = 0; dd < 256; dd += 4) {
      float4 a[5], bb[5];
#pragma unroll
      for (int r = 0; r < 5; ++r) a[r] = *(const float4*)&big[(i0 + r) * 260 + dd];
#pragma unroll
      for (int cc = 0; cc < 5; ++cc) bb[cc] = *(const float4*)&big[(j0 + cc) * 260 + dd];
#pragma unroll
      for (int r = 0; r < 5; ++r)
#pragma unroll
        for (int cc = 0; cc < 5; ++cc)
          c[r][cc] += a[r].x * bb[cc].x + a[r].y * bb[cc].y +
                      a[r].z * bb[cc].z + a[r].w * bb[cc].w;
    }
    __syncthreads();                    // all Gram reads of big done
#pragma unroll
    for (int r = 0; r < 5; ++r)
#pragma unroll
      for (int cc = 0; cc < 5; ++cc) S[i0 + r][j0 + cc] = c[r][cc];
  }
  __syncthreads();

  // ---- build Atil[k][i][j] = S[i][j]-S[i][k]-S[k][j]+S[k][k] over flat's LDS ----
  for (int e = tid; e < 19200; e += 256) {
    int k = e / 6400, rem = e - k * 6400;
    int i = rem / 80, j = rem - i * 80;
    big[k * 6560 + i * 82 + j] = S[i][j] - S[i][k] - S[k][j] + S[k][k];
  }

  // ---- power iteration, 3 k's in parallel, no per-iter reductions ----
  const int pk = (tid < 240) ? tid / 80 : 0;
  const int pi = (tid < 240) ? tid - pk * 80 : 0;
  const float* Ak = &big[pk * 6560 + pi * 82];
  if (tid < 240) vbuf[0][pk][pi] = 1.0f;
  __syncthreads();

  int cur = 0;
  for (int it = 0; it < PITER; ++it) {
    if (tid < 240) {
      const float* vk = vbuf[cur][pk];
      float u = 0.f;
#pragma unroll
      for (int j = 0; j < 80; j += 2) {
        float2 aa = *(const float2*)(Ak + j);
        float2 vv = *(const float2*)(vk + j);
        u += aa.x * vv.x + aa.y * vv.y;
      }
      vbuf[cur ^ 1][pk][pi] = u * 6.103515625e-05f;   // 2^-14 scale
    }
    __syncthreads();
    cur ^= 1;
  }

  // ---- Rayleigh quotient: lam_k = (v' A v)/(v' v) ----
  if (tid < 240) {
    const float* vk = vbuf[cur][pk];
    float u = 0.f;
#pragma unroll
    for (int j = 0; j < 80; j += 2) {
      float2 aa = *(const float2*)(Ak + j);
      float2 vv = *(const float2*)(vk + j);
      u += aa.x * vv.x + aa.y * vv.y;
    }
    float vi = vk[pi];
    redA[tid] = u * vi;
    redB[tid] = vi * vi;
  }
  __syncthreads();
#pragma unroll
  for (int s = 64; s >= 1; s >>= 1) {
    if (tid < 240 && pi < s && pi + s < 80) {
      redA[tid] += redA[tid + s];
      redB[tid] += redB[tid + s];
    }
    __syncthreads();
  }
  if (tid == 0) {
    float L0 = -0.1f * (redA[0]   / redB[0]);
    float L1 = -0.1f * (redA[80]  / redB[80]);
    float L2 = -0.1f * (redA[160] / redB[160]);
    float m = fmaxf(L0, fmaxf(L1, L2));
    float e0 = expf(L0 - m), e1 = expf(L1 - m), e2 = expf(L2 - m);
    float inv = 1.0f / (e0 + e1 + e2);
    wk[0] = e0 * inv; wk[1] = e1 * inv; wk[2] = e2 * inv;
  }
  __syncthreads();

  // ---- write relu(new_input) bf16 (reads fb from global/L2) ----
  const int d = tid;
  const float c0 = fb[0 * 256 + d], c1 = fb[1 * 256 + d], c2 = fb[2 * 256 + d];
  const float w0 = wk[0], w1 = wk[1], w2 = wk[2];
  for (int t = 0; t < 8; ++t) {
    float xs = 0.f;
#pragma unroll
    for (int o = 0; o < 10; ++o) xs += fb[(size_t)(t * 10 + o) * 256 + d];
    size_t rb = ((size_t)(b * 8 + t)) * 1024;
    Rbuf[rb + 0 * 256 + d] = f2bf(fmaxf(w0 * (xs - 10.f * c0), 0.f));
    Rbuf[rb + 1 * 256 + d] = f2bf(fmaxf(w1 * (xs - 10.f * c1), 0.f));
    Rbuf[rb + 2 * 256 + d] = f2bf(fmaxf(w2 * (xs - 10.f * c2), 0.f));
    float go = graph[((size_t)(b * 8 + t)) * 256 + d];
    Rbuf[rb + 768 + d] = f2bf(fmaxf(go, 0.f));
  }
}

// ---------------------------------------------------------------------------
// Transpose one scale's W1 (s*1024 x 512 f32) into Out[j][col][k] bf16.
__global__ __launch_bounds__(256) void w1t_kernel(
    const float* __restrict__ W1, short* __restrict__ Out)
{
  __shared__ float sh[32][33];
  const int j = blockIdx.z;
  const int k0 = blockIdx.x * 32, c0 = blockIdx.y * 32;
  const int tx = threadIdx.x & 31, ty = threadIdx.x >> 5;
#pragma unroll
  for (int q = 0; q < 4; ++q) {
    int kk = ty + q * 8;
    sh[kk][tx] = W1[(size_t)(j * 1024 + k0 + kk) * 512 + c0 + tx];
  }
  __syncthreads();
#pragma unroll
  for (int q = 0; q < 4; ++q) {
    int cc = ty + q * 8;
    Out[(size_t)(j * 512 + c0 + cc) * 1024 + k0 + tx] = f2bf(sh[tx][cc]);
  }
}

// ---------------------------------------------------------------------------
__global__ __launch_bounds__(256) void w2t_kernel(
    const float* __restrict__ w2a, const float* __restrict__ w2b,
    const float* __restrict__ w2c, const float* __restrict__ w2d,
    short* __restrict__ O)
{
  int idx = blockIdx.x * 256 + threadIdx.x;      // < 192*2048
  int col = idx >> 11, kg = idx & 2047;
  int si = kg >> 9, kr = kg & 511;
  const float* w = (si == 0) ? w2a : (si == 1) ? w2b : (si == 2) ? w2c : w2d;
  O[idx] = (col < 174) ? f2bf(w[(size_t)kr * 174 + col]) : (short)0;
}

// ---------------------------------------------------------------------------
// P(2048 x 5120) bf16 = Rbf(2048x1024) @ W1T^T; 128x128 tile, BK=32, 4 waves.
__global__ __launch_bounds__(256) void p_mfma(
    const short* __restrict__ A, const short* __restrict__ W1T,
    short* __restrict__ P)
{
  __shared__ short As[128 * 32];
  __shared__ short Bs[128 * 32];
  const int tid = threadIdx.x, lane = tid & 63, w = tid >> 6;
  const int wr = w >> 1, wc = w & 1;
  const int rowBase = blockIdx.y * 128;
  const short* Bp = W1T + (size_t)blockIdx.x * 128 * 1024;
  const int rA = w * 16 + (lane >> 2);
  const int kkA = (lane & 3) * 8;

  f32x4 acc[4][4];
#pragma unroll
  for (int m = 0; m < 4; ++m)
#pragma unroll
    for (int n = 0; n < 4; ++n) acc[m][n] = (f32x4){0.f, 0.f, 0.f, 0.f};

  for (int k0 = 0; k0 < 1024; k0 += 32) {
    __syncthreads();
    gload16(A + (size_t)(rowBase + rA) * 1024 + k0 + kkA, As + w * 512);
    gload16(A + (size_t)(rowBase + 64 + rA) * 1024 + k0 + kkA, As + 2048 + w * 512);
    gload16(Bp + (size_t)rA * 1024 + k0 + kkA, Bs + w * 512);
    gload16(Bp + (size_t)(64 + rA) * 1024 + k0 + kkA, Bs + 2048 + w * 512);
    __syncthreads();
    short8v a[4], bv[4];
#pragma unroll
    for (int m = 0; m < 4; ++m)
      a[m] = *(const short8v*)(As + (wr * 64 + m * 16 + (lane & 15)) * 32 + (lane >> 4) * 8);
#pragma unroll
    for (int n = 0; n < 4; ++n)
      bv[n] = *(const short8v*)(Bs + (wc * 64 + n * 16 + (lane & 15)) * 32 + (lane >> 4) * 8);
#pragma unroll
    for (int m = 0; m < 4; ++m)
#pragma unroll
      for (int n = 0; n < 4; ++n)
        acc[m][n] = __builtin_amdgcn_mfma_f32_16x16x32_bf16(a[m], bv[n], acc[m][n], 0, 0, 0);
  }

  const int colG = blockIdx.x * 128 + wc * 64;
#pragma unroll
  for (int m = 0; m < 4; ++m) {
    int row = rowBase + wr * 64 + m * 16 + (lane >> 4) * 4;
#pragma unroll
    for (int n = 0; n < 4; ++n) {
      int col = colG + n * 16 + (lane & 15);
#pragma unroll
      for (int r = 0; r < 4; ++r)
        P[(size_t)(row + r) * 5120 + col] = f2bf(acc[m][n][r]);
    }
  }
}

// ---------------------------------------------------------------------------
// Hsum[row][si*512+c] bf16; thread owns 2 consecutive cols (short2 loads).
__global__ __launch_bounds__(256) void hsum_all(
    const short* __restrict__ P,
    const float* __restrict__ b1a, const float* __restrict__ b1b,
    const float* __restrict__ b1c, const float* __restrict__ b1d,
    short* __restrict__ Hsum)
{
  const int row = blockIdx.x, t = row & 7, base = row - t;
  const int c0 = threadIdx.x * 2;
  const size_t prow = (size_t)base * 5120;

  {  // si=0, s=4
    float2 bb = *(const float2*)(b1a + c0);
    float a0 = 0.f, a1 = 0.f;
    for (int r = 0; r < 12; ++r) {
      if (ROWS4[r][0] != t) continue;
      float h0 = bb.x, h1 = bb.y;
#pragma unroll
      for (int jj = 0; jj < 4; ++jj) {
        const short2 pv = *(const short2*)(P + prow + (size_t)ROWS4[r][1 + jj] * 5120 + jj * 512 + c0);
        h0 += bf2f(pv.x); h1 += bf2f(pv.y);
      }
      a0 += fmaxf(h0, 0.f); a1 += fmaxf(h1, 0.f);
    }
    uint32_t wv = (uint32_t)(uint16_t)f2bf(a0) | ((uint32_t)(uint16_t)f2bf(a1) << 16);
    *(uint32_t*)&Hsum[(size_t)row * 2048 + c0] = wv;
  }
  {  // si=1, s=3
    float2 bb = *(const float2*)(b1b + c0);
    float a0 = 0.f, a1 = 0.f;
    for (int r = 0; r < 15; ++r) {
      if (ROWS3[r][0] != t) continue;
      float h0 = bb.x, h1 = bb.y;
#pragma unroll
      for (int jj = 0; jj < 3; ++jj) {
        const short2 pv = *(const short2*)(P + prow + (size_t)ROWS3[r][1 + jj] * 5120 + 2048 + jj * 512 + c0);
        h0 += bf2f(pv.x); h1 += bf2f(pv.y);
      }
      a0 += fmaxf(h0, 0.f); a1 += fmaxf(h1, 0.f);
    }
    uint32_t wv = (uint32_t)(uint16_t)f2bf(a0) | ((uint32_t)(uint16_t)f2bf(a1) << 16);
    *(uint32_t*)&Hsum[(size_t)row * 2048 + 512 + c0] = wv;
  }
  {  // si=2, s=2
    float2 bb = *(const float2*)(b1c + c0);
    float a0 = 0.f, a1 = 0.f;
    for (int r = 0; r < 19; ++r) {
      if (ROWS2[r][0] != t) continue;
      float h0 = bb.x, h1 = bb.y;
#pragma unroll
      for (int jj = 0; jj < 2; ++jj) {
        const short2 pv = *(const short2*)(P + prow + (size_t)ROWS2[r][1 + jj] * 5120 + 3584 + jj * 512 + c0);
        h0 += bf2f(pv.x); h1 += bf2f(pv.y);
      }
      a0 += fmaxf(h0, 0.f); a1 += fmaxf(h1, 0.f);
    }
    uint32_t wv = (uint32_t)(uint16_t)f2bf(a0) | ((uint32_t)(uint16_t)f2bf(a1) << 16);
    *(uint32_t*)&Hsum[(size_t)row * 2048 + 1024 + c0] = wv;
  }
  {  // si=3, s=1
    float2 bb = *(const float2*)(b1d + c0);
    float a0 = 0.f, a1 = 0.f;
    for (int r = 0; r < 36; ++r) {
      if (ROWS1[r][0] != t) continue;
      const short2 pv = *(const short2*)(P + prow + (size_t)ROWS1[r][1] * 5120 + 4608 + c0);
      a0 += fmaxf(bb.x + bf2f(pv.x), 0.f);
      a1 += fmaxf(bb.y + bf2f(pv.y), 0.f);
    }
    uint32_t wv = (uint32_t)(uint16_t)f2bf(a0) | ((uint32_t)(uint16_t)f2bf(a1) << 16);
    *(uint32_t*)&Hsum[(size_t)row * 2048 + 1536 + c0] = wv;
  }
}

// ---------------------------------------------------------------------------
// out(2048x174 f32) = Hsum(2048x2048) @ W2T^T + counted biases. grid (3,16).
__global__ __launch_bounds__(256) void out_mfma(
    const short* __restrict__ H, const short* __restrict__ W2T,
    const float* __restrict__ b2a, const float* __restrict__ b2b,
    const float* __restrict__ b2c, const float* __restrict__ b2d,
    float* __restrict__ out)
{
  __shared__ short As[128 * 32];
  __shared__ short Bs[64 * 32];
  const int tid = threadIdx.x, lane = tid & 63, w = tid >> 6;
  const int wr = w >> 1, wc = w & 1;
  const int rowBase = blockIdx.y * 128, colBase = blockIdx.x * 64;
  const int rA = w * 16 + (lane >> 2);
  const int kkA = (lane & 3) * 8;

  f32x4 acc[4][2];
#pragma unroll
  for (int m = 0; m < 4; ++m)
#pragma unroll
    for (int n = 0; n < 2; ++n) acc[m][n] = (f32x4){0.f, 0.f, 0.f, 0.f};

  for (int k0 = 0; k0 < 2048; k0 += 32) {
    __syncthreads();
    gload16(H + (size_t)(rowBase + rA) * 2048 + k0 + kkA, As + w * 512);
    gload16(H + (size_t)(rowBase + 64 + rA) * 2048 + k0 + kkA, As + 2048 + w * 512);
    gload16(W2T + (size_t)(colBase + rA) * 2048 + k0 + kkA, Bs + w * 512);
    __syncthreads();
    short8v a[4], bv[2];
#pragma unroll
    for (int m = 0; m < 4; ++m)
      a[m] = *(const short8v*)(As + (wr * 64 + m * 16 + (lane & 15)) * 32 + (lane >> 4) * 8);
#pragma unroll
    for (int n = 0; n < 2; ++n)
      bv[n] = *(const short8v*)(Bs + (wc * 32 + n * 16 + (lane & 15)) * 32 + (lane >> 4) * 8);
#pragma unroll
    for (int m = 0; m < 4; ++m)
#pragma unroll
      for (int n = 0; n < 2; ++n)
        acc[m][n] = __builtin_amdgcn_mfma_f32_16x16x32_bf16(a[m], bv[n], acc[m][n], 0, 0, 0);
  }

#pragma unroll
  for (int n = 0; n < 2; ++n) {
    int col = colBase + wc * 32 + n * 16 + (lane & 15);
    if (col >= 174) continue;
    float ba = b2a[col], bb = b2b[col], bc = b2c[col], bd = b2d[col];
#pragma unroll
    for (int m = 0; m < 4; ++m) {
      int row0 = rowBase + wr * 64 + m * 16 + (lane >> 4) * 4;
#pragma unroll
      for (int r = 0; r < 4; ++r) {
        int row = row0 + r, tt = row & 7;
        float bias = CNT[tt][0] * ba + CNT[tt][1] * bb + CNT[tt][2] * bc + CNT[tt][3] * bd;
        out[(size_t)row * 174 + col] = acc[m][n][r] + bias;
      }
    }
  }
}

// ---------------------------------------------------------------------------
extern "C" void kernel_launch(void* const* d_in, const int* in_sizes, int n_in,
                              void* d_out, int out_size, void* d_ws, size_t ws_size,
                              hipStream_t stream) {
  const float* graph = (const float*)d_in[0];
  const float* init  = (const float*)d_in[1];
  const float* w1[4] = {(const float*)d_in[3],  (const float*)d_in[7],
                        (const float*)d_in[11], (const float*)d_in[15]};
  const float* b1[4] = {(const float*)d_in[4],  (const float*)d_in[8],
                        (const float*)d_in[12], (const float*)d_in[16]};
  const float* w2[4] = {(const float*)d_in[5],  (const float*)d_in[9],
                        (const float*)d_in[13], (const float*)d_in[17]};
  const float* b2[4] = {(const float*)d_in[6],  (const float*)d_in[10],
                        (const float*)d_in[14], (const float*)d_in[18]};
  float* out = (float*)d_out;

  char* ws = (char*)d_ws;
  short* Rbf  = (short*)(ws + 0);                    // 4 MiB (dead after p_mfma)
  short* W1T  = (short*)(ws + ((size_t)4  << 20));   // 10 MiB (dead after p_mfma)
  short* P    = (short*)(ws + ((size_t)14 << 20));   // 20 MiB
  short* W2T  = (short*)(ws + ((size_t)34 << 20));   // 0.75 MiB
  short* Hsum = (short*)(ws + 0);                    // 8 MiB (reuses Rbf/W1T head)

  var_kernel<<<256, 256, 0, stream>>>(init, graph, Rbf);

  const int sliceBase[4] = {0, 4, 7, 9};
  for (int si = 0; si < 4; ++si) {
    int s = 4 - si;
    dim3 g(32, 16, s);
    w1t_kernel<<<g, 256, 0, stream>>>(w1[si], W1T + (size_t)sliceBase[si] * 512 * 1024);
  }
  w2t_kernel<<<1536, 256, 0, stream>>>(w2[0], w2[1], w2[2], w2[3], W2T);

  p_mfma<<<dim3(40, 16), 256, 0, stream>>>(Rbf, W1T, P);

  hsum_all<<<2048, 256, 0, stream>>>(P, b1[0], b1[1], b1[2], b1[3], Hsum);

  out_mfma<<<dim3(3, 16), 256, 0, stream>>>(Hsum, W2T, b2[0], b2[1], b2[2], b2[3], out);
}

// Round 4
// 110.473 us; speedup vs baseline: 7.9818x; 1.2472x over previous
//
#include <hip/hip_runtime.h>
#include <math.h>
#include <stdint.h>

// ---------------------------------------------------------------------------
// TemporalRelationGraph forward, MI355X — bf16 MFMA pipeline, round 4
// B=256, SEQ=8, NOBJ=10, SD=256, K=3, D=1024, NB=512, NC=174
//   var_kernel   : symmetric reg-tiled Gram + Atilde + 7-iter power method
//                  -> Rbf = relu(new_input) bf16 (2048x1024)
//   prep_weights : fat kernel; W1 -> W1T bf16 [10][512][1024], W2 -> W2T [192][2048]
//   p_mfma       : P(2048x5120 bf16) = Rbf @ W1T^T (XCD-swizzled grid)
//   hsum_all     : Hsum(2048x2048 bf16) windowed relu-sums
//   out_split    : split-K=4 partials f32 (2048x192 each)
//   out_reduce   : out = sum partials + counted biases
// Train/test plans identical for SEQ=8,NF=4,SUB=10 -> is_test ignored.
// ---------------------------------------------------------------------------

#define PITER 7

typedef __attribute__((ext_vector_type(8))) short short8v;
typedef __attribute__((ext_vector_type(4))) float f32x4;

__device__ __forceinline__ short f2bf(float f) {
  uint32_t u = __float_as_uint(f);
  u += 0x7fffu + ((u >> 16) & 1u);      // RNE
  return (short)(u >> 16);
}
__device__ __forceinline__ float bf2f(short s) {
  return __uint_as_float(((uint32_t)(uint16_t)s) << 16);
}
__device__ __forceinline__ void gload16(const void* g, void* l) {
  __builtin_amdgcn_global_load_lds(
      (const __attribute__((address_space(1))) void*)g,
      (__attribute__((address_space(3))) void*)l, 16, 0, 0);
}

// upper-triangular 5x5 tile list: packed = (ti<<4)|tj, ti<=tj, 16x16 grid -> 136
__device__ const uint8_t TRI[136] = {
  0x00,0x01,0x02,0x03,0x04,0x05,0x06,0x07,0x08,0x09,0x0A,0x0B,0x0C,0x0D,0x0E,0x0F,
  0x11,0x12,0x13,0x14,0x15,0x16,0x17,0x18,0x19,0x1A,0x1B,0x1C,0x1D,0x1E,0x1F,
  0x22,0x23,0x24,0x25,0x26,0x27,0x28,0x29,0x2A,0x2B,0x2C,0x2D,0x2E,0x2F,
  0x33,0x34,0x35,0x36,0x37,0x38,0x39,0x3A,0x3B,0x3C,0x3D,0x3E,0x3F,
  0x44,0x45,0x46,0x47,0x48,0x49,0x4A,0x4B,0x4C,0x4D,0x4E,0x4F,
  0x55,0x56,0x57,0x58,0x59,0x5A,0x5B,0x5C,0x5D,0x5E,0x5F,
  0x66,0x67,0x68,0x69,0x6A,0x6B,0x6C,0x6D,0x6E,0x6F,
  0x77,0x78,0x79,0x7A,0x7B,0x7C,0x7D,0x7E,0x7F,
  0x88,0x89,0x8A,0x8B,0x8C,0x8D,0x8E,0x8F,
  0x99,0x9A,0x9B,0x9C,0x9D,0x9E,0x9F,
  0xAA,0xAB,0xAC,0xAD,0xAE,0xAF,
  0xBB,0xBC,0xBD,0xBE,0xBF,
  0xCC,0xCD,0xCE,0xCF,
  0xDD,0xDE,0xDF,
  0xEE,0xEF,
  0xFF,
};

__device__ const int8_t ROWS4[12][5] = {
  {3, 0,1,2,3},
  {4, 0,1,2,3},{4, 1,2,3,4},
  {5, 0,1,2,3},{5, 1,2,3,4},{5, 2,3,4,5},
  {6, 0,1,2,3},{6, 1,2,3,4},{6, 2,3,4,5},{6, 3,4,5,6},
  {7, 0,2,4,6},{7, 1,3,5,7},
};
__device__ const int8_t ROWS3[15][4] = {
  {2, 0,1,2},
  {3, 0,1,2},{3, 1,2,3},
  {4, 0,1,2},{4, 1,2,3},{4, 2,3,4},
  {5, 0,2,4},{5, 1,3,5},
  {6, 0,2,4},{6, 1,3,5},{6, 2,4,6},
  {7, 0,2,4},{7, 1,3,5},{7, 2,4,6},{7, 3,5,7},
};
__device__ const int8_t ROWS2[19][3] = {
  {1, 0,1},
  {2, 0,1},{2, 1,2},
  {3, 0,2},{3, 1,3},
  {4, 0,2},{4, 1,3},{4, 2,4},
  {5, 0,3},{5, 1,4},{5, 2,5},
  {6, 0,3},{6, 1,4},{6, 2,5},{6, 3,6},
  {7, 0,4},{7, 1,5},{7, 2,6},{7, 3,7},
};
__device__ const int8_t ROWS1[36][2] = {
  {0,0},
  {1,0},{1,1},
  {2,0},{2,1},{2,2},
  {3,0},{3,1},{3,2},{3,3},
  {4,0},{4,1},{4,2},{4,3},{4,4},
  {5,0},{5,1},{5,2},{5,3},{5,4},{5,5},
  {6,0},{6,1},{6,2},{6,3},{6,4},{6,5},{6,6},
  {7,0},{7,1},{7,2},{7,3},{7,4},{7,5},{7,6},{7,7},
};
// window counts per (t, scale-index): si 0->s4, 1->s3, 2->s2, 3->s1
__device__ const float CNT[8][4] = {
  {0,0,0,1},{0,0,1,2},{0,1,2,3},{1,2,2,4},
  {2,3,3,5},{3,2,3,6},{4,3,4,7},{2,4,4,8},
};

// ---------------------------------------------------------------------------
// One block per batch (256 blocks, 256 threads). LDS ~113 KB -> 1 block/CU.
__global__ __launch_bounds__(256) void var_kernel(
    const float* __restrict__ init, const float* __restrict__ graph,
    short* __restrict__ Rbuf)
{
  __shared__ float S[80][81];
  __shared__ float big[20800];      // flat[80][260] then Atil[3][80][82]
  __shared__ float vbuf[2][3][84];
  __shared__ float redA[240];
  __shared__ float redB[240];
  __shared__ float wk[3];

  const int b = blockIdx.x;
  const int tid = threadIdx.x;
  const float* fb = init + (size_t)b * 80 * 256;

  // ---- stage flat[b] into LDS, row stride 260 floats ----
#pragma unroll
  for (int it = 0; it < 20; ++it) {
    int q = it * 256 + tid;             // 5120 float4s
    int r = q >> 6, c4 = q & 63;
    float4 v = *(const float4*)(fb + (size_t)r * 256 + c4 * 4);
    *(float4*)&big[r * 260 + c4 * 4] = v;
  }
  __syncthreads();

  // ---- symmetric Gram: 136 threads, upper 5x5 tiles ----
  if (tid < 136) {
    const int pk = TRI[tid];
    const int i0 = (pk >> 4) * 5, j0 = (pk & 15) * 5;
    float c[5][5];
#pragma unroll
    for (int r = 0; r < 5; ++r)
#pragma unroll
      for (int cc = 0; cc < 5; ++cc) c[r][cc] = 0.f;

    for (int dd = 0; dd < 256; dd += 4) {
      float4 a[5], bb[5];
#pragma unroll
      for (int r = 0; r < 5; ++r) a[r] = *(const float4*)&big[(i0 + r) * 260 + dd];
#pragma unroll
      for (int cc = 0; cc < 5; ++cc) bb[cc] = *(const float4*)&big[(j0 + cc) * 260 + dd];
#pragma unroll
      for (int r = 0; r < 5; ++r)
#pragma unroll
        for (int cc = 0; cc < 5; ++cc)
          c[r][cc] += a[r].x * bb[cc].x + a[r].y * bb[cc].y +
                      a[r].z * bb[cc].z + a[r].w * bb[cc].w;
    }
#pragma unroll
    for (int r = 0; r < 5; ++r)
#pragma unroll
      for (int cc = 0; cc < 5; ++cc) {
        S[i0 + r][j0 + cc] = c[r][cc];
        S[j0 + cc][i0 + r] = c[r][cc];
      }
  }
  __syncthreads();                      // S done; all Gram reads of big done

  // ---- Atil[k][i][j] = S[i][j]-S[i][k]-S[k][j]+S[k][k] (overwrites flat) ----
  for (int e = tid; e < 19200; e += 256) {
    int k = e / 6400, rem = e - k * 6400;
    int i = rem / 80, j = rem - i * 80;
    big[k * 6560 + i * 82 + j] = S[i][j] - S[i][k] - S[k][j] + S[k][k];
  }

  // ---- power iteration, 3 k's in parallel, scale-only normalization ----
  const int pk = (tid < 240) ? tid / 80 : 0;
  const int pi = (tid < 240) ? tid - pk * 80 : 0;
  const float* Ak = &big[pk * 6560 + pi * 82];
  if (tid < 240) vbuf[0][pk][pi] = 1.0f;
  __syncthreads();

  int cur = 0;
  for (int it = 0; it < PITER; ++it) {
    if (tid < 240) {
      const float* vk = vbuf[cur][pk];
      float u = 0.f;
#pragma unroll
      for (int j = 0; j < 80; j += 2) {
        float2 aa = *(const float2*)(Ak + j);
        float2 vv = *(const float2*)(vk + j);
        u += aa.x * vv.x + aa.y * vv.y;
      }
      vbuf[cur ^ 1][pk][pi] = u * 6.103515625e-05f;   // 2^-14 scale
    }
    __syncthreads();
    cur ^= 1;
  }

  // ---- Rayleigh quotient ----
  if (tid < 240) {
    const float* vk = vbuf[cur][pk];
    float u = 0.f;
#pragma unroll
    for (int j = 0; j < 80; j += 2) {
      float2 aa = *(const float2*)(Ak + j);
      float2 vv = *(const float2*)(vk + j);
      u += aa.x * vv.x + aa.y * vv.y;
    }
    float vi = vk[pi];
    redA[tid] = u * vi;
    redB[tid] = vi * vi;
  }
  __syncthreads();
#pragma unroll
  for (int s = 64; s >= 1; s >>= 1) {
    if (tid < 240 && pi < s && pi + s < 80) {
      redA[tid] += redA[tid + s];
      redB[tid] += redB[tid + s];
    }
    __syncthreads();
  }
  if (tid == 0) {
    float L0 = -0.1f * (redA[0]   / redB[0]);
    float L1 = -0.1f * (redA[80]  / redB[80]);
    float L2 = -0.1f * (redA[160] / redB[160]);
    float m = fmaxf(L0, fmaxf(L1, L2));
    float e0 = expf(L0 - m), e1 = expf(L1 - m), e2 = expf(L2 - m);
    float inv = 1.0f / (e0 + e1 + e2);
    wk[0] = e0 * inv; wk[1] = e1 * inv; wk[2] = e2 * inv;
  }
  __syncthreads();

  // ---- write relu(new_input) bf16 (fb rows are L2/L3-warm) ----
  const int d = tid;
  const float c0 = fb[0 * 256 + d], c1 = fb[1 * 256 + d], c2 = fb[2 * 256 + d];
  const float w0 = wk[0], w1 = wk[1], w2 = wk[2];
  for (int t = 0; t < 8; ++t) {
    float xs = 0.f;
#pragma unroll
    for (int o = 0; o < 10; ++o) xs += fb[(size_t)(t * 10 + o) * 256 + d];
    size_t rb = ((size_t)(b * 8 + t)) * 1024;
    Rbuf[rb + 0 * 256 + d] = f2bf(fmaxf(w0 * (xs - 10.f * c0), 0.f));
    Rbuf[rb + 1 * 256 + d] = f2bf(fmaxf(w1 * (xs - 10.f * c1), 0.f));
    Rbuf[rb + 2 * 256 + d] = f2bf(fmaxf(w2 * (xs - 10.f * c2), 0.f));
    float go = graph[((size_t)(b * 8 + t)) * 256 + d];
    Rbuf[rb + 768 + d] = f2bf(fmaxf(go, 0.f));
  }
}

// ---------------------------------------------------------------------------
// Fat prep kernel: blocks [0,5120) transpose W1 slices; [5120,6656) build W2T.
__global__ __launch_bounds__(256) void prep_weights(
    const float* __restrict__ w1_4, const float* __restrict__ w1_3,
    const float* __restrict__ w1_2, const float* __restrict__ w1_1,
    const float* __restrict__ w2a, const float* __restrict__ w2b,
    const float* __restrict__ w2c, const float* __restrict__ w2d,
    short* __restrict__ W1T, short* __restrict__ W2T)
{
  __shared__ float sh[32][33];
  const int blk = blockIdx.x;
  if (blk < 5120) {
    const int slice = blk >> 9, rem = blk & 511;
    const int k0 = (rem & 31) * 32, c0 = (rem >> 5) * 32;
    const float* W1; int j;
    if (slice < 4)      { W1 = w1_4; j = slice; }
    else if (slice < 7) { W1 = w1_3; j = slice - 4; }
    else if (slice < 9) { W1 = w1_2; j = slice - 7; }
    else                { W1 = w1_1; j = 0; }
    const int tx = threadIdx.x & 31, ty = threadIdx.x >> 5;
#pragma unroll
    for (int q = 0; q < 4; ++q) {
      int kk = ty + q * 8;
      sh[kk][tx] = W1[(size_t)(j * 1024 + k0 + kk) * 512 + c0 + tx];
    }
    __syncthreads();
#pragma unroll
    for (int q = 0; q < 4; ++q) {
      int cc = ty + q * 8;
      W1T[(size_t)(slice * 512 + c0 + cc) * 1024 + k0 + tx] = f2bf(sh[tx][cc]);
    }
  } else {
    int idx = (blk - 5120) * 256 + threadIdx.x;    // < 192*2048
    int col = idx >> 11, kg = idx & 2047;
    int si = kg >> 9, kr = kg & 511;
    const float* w = (si == 0) ? w2a : (si == 1) ? w2b : (si == 2) ? w2c : w2d;
    W2T[idx] = (col < 174) ? f2bf(w[(size_t)kr * 174 + col]) : (short)0;
  }
}

// ---------------------------------------------------------------------------
// P(2048 x 5120) bf16 = Rbf(2048x1024) @ W1T^T; 128x128 tile, BK=32, 4 waves.
// Grid (40,16) with bijective XCD-chunked swizzle (B-panel-major).
__global__ __launch_bounds__(256) void p_mfma(
    const short* __restrict__ A, const short* __restrict__ W1T,
    short* __restrict__ P)
{
  __shared__ short As[128 * 32];
  __shared__ short Bs[128 * 32];
  const int id = blockIdx.x + blockIdx.y * 40;     // 640 = 8 XCD * 80
  const int nid = (id & 7) * 80 + (id >> 3);
  const int bx = nid >> 4, by = nid & 15;          // bx 0..39, by 0..15
  const int tid = threadIdx.x, lane = tid & 63, w = tid >> 6;
  const int wr = w >> 1, wc = w & 1;
  const int rowBase = by * 128;
  const short* Bp = W1T + (size_t)bx * 128 * 1024;
  const int rA = w * 16 + (lane >> 2);
  const int kkA = (lane & 3) * 8;

  f32x4 acc[4][4];
#pragma unroll
  for (int m = 0; m < 4; ++m)
#pragma unroll
    for (int n = 0; n < 4; ++n) acc[m][n] = (f32x4){0.f, 0.f, 0.f, 0.f};

  for (int k0 = 0; k0 < 1024; k0 += 32) {
    __syncthreads();
    gload16(A + (size_t)(rowBase + rA) * 1024 + k0 + kkA, As + w * 512);
    gload16(A + (size_t)(rowBase + 64 + rA) * 1024 + k0 + kkA, As + 2048 + w * 512);
    gload16(Bp + (size_t)rA * 1024 + k0 + kkA, Bs + w * 512);
    gload16(Bp + (size_t)(64 + rA) * 1024 + k0 + kkA, Bs + 2048 + w * 512);
    __syncthreads();
    short8v a[4], bv[4];
#pragma unroll
    for (int m = 0; m < 4; ++m)
      a[m] = *(const short8v*)(As + (wr * 64 + m * 16 + (lane & 15)) * 32 + (lane >> 4) * 8);
#pragma unroll
    for (int n = 0; n < 4; ++n)
      bv[n] = *(const short8v*)(Bs + (wc * 64 + n * 16 + (lane & 15)) * 32 + (lane >> 4) * 8);
#pragma unroll
    for (int m = 0; m < 4; ++m)
#pragma unroll
      for (int n = 0; n < 4; ++n)
        acc[m][n] = __builtin_amdgcn_mfma_f32_16x16x32_bf16(a[m], bv[n], acc[m][n], 0, 0, 0);
  }

  const int colG = bx * 128 + wc * 64;
#pragma unroll
  for (int m = 0; m < 4; ++m) {
    int row = rowBase + wr * 64 + m * 16 + (lane >> 4) * 4;
#pragma unroll
    for (int n = 0; n < 4; ++n) {
      int col = colG + n * 16 + (lane & 15);
#pragma unroll
      for (int r = 0; r < 4; ++r)
        P[(size_t)(row + r) * 5120 + col] = f2bf(acc[m][n][r]);
    }
  }
}

// ---------------------------------------------------------------------------
// Hsum[row][si*512+c] bf16; thread owns 2 consecutive cols (short2 loads).
__global__ __launch_bounds__(256) void hsum_all(
    const short* __restrict__ P,
    const float* __restrict__ b1a, const float* __restrict__ b1b,
    const float* __restrict__ b1c, const float* __restrict__ b1d,
    short* __restrict__ Hsum)
{
  const int row = blockIdx.x, t = row & 7, base = row - t;
  const int c0 = threadIdx.x * 2;
  const size_t prow = (size_t)base * 5120;

  {  // si=0, s=4
    float2 bb = *(const float2*)(b1a + c0);
    float a0 = 0.f, a1 = 0.f;
    for (int r = 0; r < 12; ++r) {
      if (ROWS4[r][0] != t) continue;
      float h0 = bb.x, h1 = bb.y;
#pragma unroll
      for (int jj = 0; jj < 4; ++jj) {
        const short2 pv = *(const short2*)(P + prow + (size_t)ROWS4[r][1 + jj] * 5120 + jj * 512 + c0);
        h0 += bf2f(pv.x); h1 += bf2f(pv.y);
      }
      a0 += fmaxf(h0, 0.f); a1 += fmaxf(h1, 0.f);
    }
    uint32_t wv = (uint32_t)(uint16_t)f2bf(a0) | ((uint32_t)(uint16_t)f2bf(a1) << 16);
    *(uint32_t*)&Hsum[(size_t)row * 2048 + c0] = wv;
  }
  {  // si=1, s=3
    float2 bb = *(const float2*)(b1b + c0);
    float a0 = 0.f, a1 = 0.f;
    for (int r = 0; r < 15; ++r) {
      if (ROWS3[r][0] != t) continue;
      float h0 = bb.x, h1 = bb.y;
#pragma unroll
      for (int jj = 0; jj < 3; ++jj) {
        const short2 pv = *(const short2*)(P + prow + (size_t)ROWS3[r][1 + jj] * 5120 + 2048 + jj * 512 + c0);
        h0 += bf2f(pv.x); h1 += bf2f(pv.y);
      }
      a0 += fmaxf(h0, 0.f); a1 += fmaxf(h1, 0.f);
    }
    uint32_t wv = (uint32_t)(uint16_t)f2bf(a0) | ((uint32_t)(uint16_t)f2bf(a1) << 16);
    *(uint32_t*)&Hsum[(size_t)row * 2048 + 512 + c0] = wv;
  }
  {  // si=2, s=2
    float2 bb = *(const float2*)(b1c + c0);
    float a0 = 0.f, a1 = 0.f;
    for (int r = 0; r < 19; ++r) {
      if (ROWS2[r][0] != t) continue;
      float h0 = bb.x, h1 = bb.y;
#pragma unroll
      for (int jj = 0; jj < 2; ++jj) {
        const short2 pv = *(const short2*)(P + prow + (size_t)ROWS2[r][1 + jj] * 5120 + 3584 + jj * 512 + c0);
        h0 += bf2f(pv.x); h1 += bf2f(pv.y);
      }
      a0 += fmaxf(h0, 0.f); a1 += fmaxf(h1, 0.f);
    }
    uint32_t wv = (uint32_t)(uint16_t)f2bf(a0) | ((uint32_t)(uint16_t)f2bf(a1) << 16);
    *(uint32_t*)&Hsum[(size_t)row * 2048 + 1024 + c0] = wv;
  }
  {  // si=3, s=1
    float2 bb = *(const float2*)(b1d + c0);
    float a0 = 0.f, a1 = 0.f;
    for (int r = 0; r < 36; ++r) {
      if (ROWS1[r][0] != t) continue;
      const short2 pv = *(const short2*)(P + prow + (size_t)ROWS1[r][1] * 5120 + 4608 + c0);
      a0 += fmaxf(bb.x + bf2f(pv.x), 0.f);
      a1 += fmaxf(bb.y + bf2f(pv.y), 0.f);
    }
    uint32_t wv = (uint32_t)(uint16_t)f2bf(a0) | ((uint32_t)(uint16_t)f2bf(a1) << 16);
    *(uint32_t*)&Hsum[(size_t)row * 2048 + 1536 + c0] = wv;
  }
}

// ---------------------------------------------------------------------------
// Split-K out GEMM: partial[z][2048][192] = Hsum[:, z*512:(z+1)*512] @ W2T^T.
// Grid (3,16,4); 128x64 tile; no bias here.
__global__ __launch_bounds__(256) void out_split(
    const short* __restrict__ H, const short* __restrict__ W2T,
    float* __restrict__ partial)
{
  __shared__ short As[128 * 32];
  __shared__ short Bs[64 * 32];
  const int tid = threadIdx.x, lane = tid & 63, w = tid >> 6;
  const int wr = w >> 1, wc = w & 1;
  const int rowBase = blockIdx.y * 128, colBase = blockIdx.x * 64;
  const int kBase = blockIdx.z * 512;
  const int rA = w * 16 + (lane >> 2);
  const int kkA = (lane & 3) * 8;

  f32x4 acc[4][2];
#pragma unroll
  for (int m = 0; m < 4; ++m)
#pragma unroll
    for (int n = 0; n < 2; ++n) acc[m][n] = (f32x4){0.f, 0.f, 0.f, 0.f};

  for (int k0 = 0; k0 < 512; k0 += 32) {
    const int kg = kBase + k0;
    __syncthreads();
    gload16(H + (size_t)(rowBase + rA) * 2048 + kg + kkA, As + w * 512);
    gload16(H + (size_t)(rowBase + 64 + rA) * 2048 + kg + kkA, As + 2048 + w * 512);
    gload16(W2T + (size_t)(colBase + rA) * 2048 + kg + kkA, Bs + w * 512);
    __syncthreads();
    short8v a[4], bv[2];
#pragma unroll
    for (int m = 0; m < 4; ++m)
      a[m] = *(const short8v*)(As + (wr * 64 + m * 16 + (lane & 15)) * 32 + (lane >> 4) * 8);
#pragma unroll
    for (int n = 0; n < 2; ++n)
      bv[n] = *(const short8v*)(Bs + (wc * 32 + n * 16 + (lane & 15)) * 32 + (lane >> 4) * 8);
#pragma unroll
    for (int m = 0; m < 4; ++m)
#pragma unroll
      for (int n = 0; n < 2; ++n)
        acc[m][n] = __builtin_amdgcn_mfma_f32_16x16x32_bf16(a[m], bv[n], acc[m][n], 0, 0, 0);
  }

  float* pz = partial + (size_t)blockIdx.z * 2048 * 192;
#pragma unroll
  for (int n = 0; n < 2; ++n) {
    int col = colBase + wc * 32 + n * 16 + (lane & 15);
#pragma unroll
    for (int m = 0; m < 4; ++m) {
      int row0 = rowBase + wr * 64 + m * 16 + (lane >> 4) * 4;
#pragma unroll
      for (int r = 0; r < 4; ++r)
        pz[(size_t)(row0 + r) * 192 + col] = acc[m][n][r];
    }
  }
}

// ---------------------------------------------------------------------------
__global__ __launch_bounds__(256) void out_reduce(
    const float* __restrict__ partial,
    const float* __restrict__ b2a, const float* __restrict__ b2b,
    const float* __restrict__ b2c, const float* __restrict__ b2d,
    float* __restrict__ out)
{
  const int row = blockIdx.x, col = threadIdx.x;
  if (col >= 174) return;
  const size_t o = (size_t)row * 192 + col;
  float s = partial[o] + partial[o + (size_t)2048 * 192]
          + partial[o + (size_t)4096 * 192] + partial[o + (size_t)6144 * 192];
  int tt = row & 7;
  float bias = CNT[tt][0] * b2a[col] + CNT[tt][1] * b2b[col]
             + CNT[tt][2] * b2c[col] + CNT[tt][3] * b2d[col];
  out[(size_t)row * 174 + col] = s + bias;
}

// ---------------------------------------------------------------------------
extern "C" void kernel_launch(void* const* d_in, const int* in_sizes, int n_in,
                              void* d_out, int out_size, void* d_ws, size_t ws_size,
                              hipStream_t stream) {
  const float* graph = (const float*)d_in[0];
  const float* init  = (const float*)d_in[1];
  const float* w1[4] = {(const float*)d_in[3],  (const float*)d_in[7],
                        (const float*)d_in[11], (const float*)d_in[15]};
  const float* b1[4] = {(const float*)d_in[4],  (const float*)d_in[8],
                        (const float*)d_in[12], (const float*)d_in[16]};
  const float* w2[4] = {(const float*)d_in[5],  (const float*)d_in[9],
                        (const float*)d_in[13], (const float*)d_in[17]};
  const float* b2[4] = {(const float*)d_in[6],  (const float*)d_in[10],
                        (const float*)d_in[14], (const float*)d_in[18]};
  float* out = (float*)d_out;

  char* ws = (char*)d_ws;
  short* Rbf  = (short*)(ws + 0);                    // 4 MiB   (dead after p_mfma)
  short* W1T  = (short*)(ws + ((size_t)4  << 20));   // 10 MiB  (dead after p_mfma)
  short* P    = (short*)(ws + ((size_t)14 << 20));   // 20 MiB  (dead after hsum_all)
  short* W2T  = (short*)(ws + ((size_t)34 << 20));   // 0.75 MiB
  short* Hsum = (short*)(ws + 0);                    // 8 MiB   (over Rbf/W1T head)
  float* Part = (float*)(ws + ((size_t)8 << 20));    // 6.29 MiB (over W1T tail/P head)

  var_kernel<<<256, 256, 0, stream>>>(init, graph, Rbf);

  prep_weights<<<6656, 256, 0, stream>>>(w1[0], w1[1], w1[2], w1[3],
                                         w2[0], w2[1], w2[2], w2[3], W1T, W2T);

  p_mfma<<<dim3(40, 16), 256, 0, stream>>>(Rbf, W1T, P);

  hsum_all<<<2048, 256, 0, stream>>>(P, b1[0], b1[1], b1[2], b1[3], Hsum);

  out_split<<<dim3(3, 16, 4), 256, 0, stream>>>(Hsum, W2T, Part);

  out_reduce<<<2048, 256, 0, stream>>>(Part, b2[0], b2[1], b2[2], b2[3], out);
}

// Round 5
// 104.439 us; speedup vs baseline: 8.4430x; 1.0578x over previous
//
#include <hip/hip_runtime.h>
#include <math.h>
#include <stdint.h>

// ---------------------------------------------------------------------------
// TemporalRelationGraph forward, MI355X — bf16 MFMA pipeline, round 5
// B=256, SEQ=8, NOBJ=10, SD=256, K=3, D=1024, NB=512, NC=174
//   var_kernel   : 512-thread latency-optimized Gram + power method
//                  -> Rbf = relu(new_input) bf16 (2048x1024)
//   prep_weights : W1 -> W1T bf16 [10][512][1024], W2 -> W2T [192][2048]
//   p_mfma       : P(2048x5120 bf16) = Rbf @ W1T^T (XCD-swizzled grid)
//   hsum_all     : Hsum(2048x2048 bf16) windowed relu-sums
//   out_split    : split-K=4 partials f32 (2048x192 each)
//   out_reduce   : out = sum partials + counted biases
// Train/test plans identical for SEQ=8,NF=4,SUB=10 -> is_test ignored.
// ---------------------------------------------------------------------------

#define PITER 4

typedef __attribute__((ext_vector_type(8))) short short8v;
typedef __attribute__((ext_vector_type(4))) short short4v;
typedef __attribute__((ext_vector_type(4))) float f32x4;

__device__ __forceinline__ short f2bf(float f) {
  uint32_t u = __float_as_uint(f);
  u += 0x7fffu + ((u >> 16) & 1u);      // RNE
  return (short)(u >> 16);
}
__device__ __forceinline__ float bf2f(short s) {
  return __uint_as_float(((uint32_t)(uint16_t)s) << 16);
}
__device__ __forceinline__ void gload16(const void* g, void* l) {
  __builtin_amdgcn_global_load_lds(
      (const __attribute__((address_space(1))) void*)g,
      (__attribute__((address_space(3))) void*)l, 16, 0, 0);
}

// upper-triangular 5x5 tile list: packed = (ti<<4)|tj, ti<=tj -> 136 tiles
__device__ const uint8_t TRI[136] = {
  0x00,0x01,0x02,0x03,0x04,0x05,0x06,0x07,0x08,0x09,0x0A,0x0B,0x0C,0x0D,0x0E,0x0F,
  0x11,0x12,0x13,0x14,0x15,0x16,0x17,0x18,0x19,0x1A,0x1B,0x1C,0x1D,0x1E,0x1F,
  0x22,0x23,0x24,0x25,0x26,0x27,0x28,0x29,0x2A,0x2B,0x2C,0x2D,0x2E,0x2F,
  0x33,0x34,0x35,0x36,0x37,0x38,0x39,0x3A,0x3B,0x3C,0x3D,0x3E,0x3F,
  0x44,0x45,0x46,0x47,0x48,0x49,0x4A,0x4B,0x4C,0x4D,0x4E,0x4F,
  0x55,0x56,0x57,0x58,0x59,0x5A,0x5B,0x5C,0x5D,0x5E,0x5F,
  0x66,0x67,0x68,0x69,0x6A,0x6B,0x6C,0x6D,0x6E,0x6F,
  0x77,0x78,0x79,0x7A,0x7B,0x7C,0x7D,0x7E,0x7F,
  0x88,0x89,0x8A,0x8B,0x8C,0x8D,0x8E,0x8F,
  0x99,0x9A,0x9B,0x9C,0x9D,0x9E,0x9F,
  0xAA,0xAB,0xAC,0xAD,0xAE,0xAF,
  0xBB,0xBC,0xBD,0xBE,0xBF,
  0xCC,0xCD,0xCE,0xCF,
  0xDD,0xDE,0xDF,
  0xEE,0xEF,
  0xFF,
};

__device__ const int8_t ROWS4[12][5] = {
  {3, 0,1,2,3},
  {4, 0,1,2,3},{4, 1,2,3,4},
  {5, 0,1,2,3},{5, 1,2,3,4},{5, 2,3,4,5},
  {6, 0,1,2,3},{6, 1,2,3,4},{6, 2,3,4,5},{6, 3,4,5,6},
  {7, 0,2,4,6},{7, 1,3,5,7},
};
__device__ const int8_t ROWS3[15][4] = {
  {2, 0,1,2},
  {3, 0,1,2},{3, 1,2,3},
  {4, 0,1,2},{4, 1,2,3},{4, 2,3,4},
  {5, 0,2,4},{5, 1,3,5},
  {6, 0,2,4},{6, 1,3,5},{6, 2,4,6},
  {7, 0,2,4},{7, 1,3,5},{7, 2,4,6},{7, 3,5,7},
};
__device__ const int8_t ROWS2[19][3] = {
  {1, 0,1},
  {2, 0,1},{2, 1,2},
  {3, 0,2},{3, 1,3},
  {4, 0,2},{4, 1,3},{4, 2,4},
  {5, 0,3},{5, 1,4},{5, 2,5},
  {6, 0,3},{6, 1,4},{6, 2,5},{6, 3,6},
  {7, 0,4},{7, 1,5},{7, 2,6},{7, 3,7},
};
__device__ const int8_t ROWS1[36][2] = {
  {0,0},
  {1,0},{1,1},
  {2,0},{2,1},{2,2},
  {3,0},{3,1},{3,2},{3,3},
  {4,0},{4,1},{4,2},{4,3},{4,4},
  {5,0},{5,1},{5,2},{5,3},{5,4},{5,5},
  {6,0},{6,1},{6,2},{6,3},{6,4},{6,5},{6,6},
  {7,0},{7,1},{7,2},{7,3},{7,4},{7,5},{7,6},{7,7},
};
// window counts per (t, scale-index): si 0->s4, 1->s3, 2->s2, 3->s1
__device__ const float CNT[8][4] = {
  {0,0,0,1},{0,0,1,2},{0,1,2,3},{1,2,2,4},
  {2,3,3,5},{3,2,3,6},{4,3,4,7},{2,4,4,8},
};

// ---------------------------------------------------------------------------
// One block per batch (256 blocks, 512 threads = 8 waves, 1 block/CU by LDS).
// Phases: stage | Gram(2-way dd-split, 272t) ∥ xsum+cent(240t) | combine |
//         Atil | 4x power-iter (480t, float4) | Rayleigh (shfl) | tail write.
__global__ __launch_bounds__(512) void var_kernel(
    const float* __restrict__ init, const float* __restrict__ graph,
    short* __restrict__ Rbuf)
{
  __shared__ __align__(16) float big[20800];   // flat[80][260] -> Atil[3][80][84]
  __shared__ float S[80][81];
  __shared__ float S2d[16][25];                // h1 partials of diagonal tiles
  __shared__ __align__(16) float xsum[8][256];
  __shared__ __align__(16) float cent[3][256];
  __shared__ __align__(16) float vbuf[2][3][84];
  __shared__ float pbuf[512];
  __shared__ float uu[3][80];
  __shared__ float lamS[3];
  __shared__ float wk[3];

  const int b = blockIdx.x;
  const int tid = threadIdx.x;
  const float* fb = init + (size_t)b * 80 * 256;

  // ---- stage flat[b] into LDS, row stride 260 ----
#pragma unroll
  for (int it = 0; it < 10; ++it) {
    int q = it * 512 + tid;             // 5120 float4s
    int r = q >> 6, c4 = q & 63;
    *(float4*)&big[r * 260 + c4 * 4] = *(const float4*)(fb + (size_t)r * 256 + c4 * 4);
  }
  __syncthreads();

  // ---- Gram halves (tid<272)  ||  xsum + centers (tid>=272) ----
  if (tid < 272) {
    const int h = (tid >= 136) ? 1 : 0;
    const int tI = tid - 136 * h;
    const int pk = TRI[tI];
    const int ti = pk >> 4, tj = pk & 15;
    const int i0 = ti * 5, j0 = tj * 5;
    const int d0 = h * 128;
    float c[5][5];
#pragma unroll
    for (int r = 0; r < 5; ++r)
#pragma unroll
      for (int cc = 0; cc < 5; ++cc) c[r][cc] = 0.f;

    for (int dd = d0; dd < d0 + 128; dd += 4) {
      float4 a[5], bb[5];
#pragma unroll
      for (int r = 0; r < 5; ++r) a[r] = *(const float4*)&big[(i0 + r) * 260 + dd];
#pragma unroll
      for (int cc = 0; cc < 5; ++cc) bb[cc] = *(const float4*)&big[(j0 + cc) * 260 + dd];
#pragma unroll
      for (int r = 0; r < 5; ++r)
#pragma unroll
        for (int cc = 0; cc < 5; ++cc)
          c[r][cc] += a[r].x * bb[cc].x + a[r].y * bb[cc].y +
                      a[r].z * bb[cc].z + a[r].w * bb[cc].w;
    }
    if (h == 0) {
#pragma unroll
      for (int r = 0; r < 5; ++r)
#pragma unroll
        for (int cc = 0; cc < 5; ++cc) S[i0 + r][j0 + cc] = c[r][cc];
    } else if (ti == tj) {
#pragma unroll
      for (int r = 0; r < 5; ++r)
#pragma unroll
        for (int cc = 0; cc < 5; ++cc) S2d[ti][r * 5 + cc] = c[r][cc];
    } else {
#pragma unroll
      for (int r = 0; r < 5; ++r)
#pragma unroll
        for (int cc = 0; cc < 5; ++cc) S[j0 + cc][i0 + r] = c[r][cc];
    }
  } else {
    const int idx = tid - 272;          // 0..239
    for (int p = idx; p < 2048; p += 240) {
      int t = p >> 8, d = p & 255;
      float s = 0.f;
#pragma unroll
      for (int o = 0; o < 10; ++o) s += big[(t * 10 + o) * 260 + d];
      xsum[t][d] = s;
    }
    for (int p = idx; p < 768; p += 240)
      cent[p >> 8][p & 255] = big[(p >> 8) * 260 + (p & 255)];
  }
  __syncthreads();

  // ---- combine halves into full symmetric S ----
  for (int e = tid; e < 3400; e += 512) {
    int tI = e / 25, rc = e - tI * 25;
    int pk = TRI[tI];
    int ti = pk >> 4, tj = pk & 15;
    int r = rc / 5, cc = rc - r * 5;
    int i = ti * 5 + r, j = tj * 5 + cc;
    float a = S[i][j];
    float b2 = (ti == tj) ? S2d[ti][rc] : S[j][i];
    float s = a + b2;
    S[i][j] = s;
    S[j][i] = s;
  }
  __syncthreads();

  // ---- Atil[k][i][j] = S[i][j]-S[i][k]-S[k][j]+S[k][k], row stride 84 ----
  for (int e = tid; e < 19200; e += 512) {
    int k = e / 6400, rem = e - k * 6400;
    int i = rem / 80, j = rem - i * 80;
    big[k * 6720 + i * 84 + j] = S[i][j] - S[i][k] - S[k][j] + S[k][k];
  }
  if (tid < 240) vbuf[0][tid / 80][tid - (tid / 80) * 80] = 1.0f;
  __syncthreads();

  // ---- power iteration: 480 threads = (k, half, i), float4 dots ----
  const int pw_k = (tid < 480) ? tid / 160 : 0;
  const int pw_rem = (tid < 480) ? tid - pw_k * 160 : 0;
  const int pw_h = pw_rem / 80, pw_i = pw_rem - pw_h * 80;
  const float* Ak = &big[pw_k * 6720 + pw_i * 84 + pw_h * 40];

  int cur = 0;
  for (int it = 0; it < PITER; ++it) {
    if (tid < 480) {
      const float* vk = &vbuf[cur][pw_k][pw_h * 40];
      float u = 0.f;
#pragma unroll
      for (int q = 0; q < 10; ++q) {
        f32x4 aa = *(const f32x4*)(Ak + q * 4);
        f32x4 vv = *(const f32x4*)(vk + q * 4);
        u += aa.x * vv.x + aa.y * vv.y + aa.z * vv.z + aa.w * vv.w;
      }
      pbuf[tid] = u;
    }
    __syncthreads();
    if (tid < 240) {
      int k = tid / 80, i = tid - k * 80;
      float u = pbuf[k * 160 + i] + pbuf[k * 160 + 80 + i];
      vbuf[cur ^ 1][k][i] = u * 6.103515625e-05f;   // 2^-14 scale
    }
    __syncthreads();
    cur ^= 1;
  }

  // ---- final matvec (unscaled) for Rayleigh ----
  if (tid < 480) {
    const float* vk = &vbuf[cur][pw_k][pw_h * 40];
    float u = 0.f;
#pragma unroll
    for (int q = 0; q < 10; ++q) {
      f32x4 aa = *(const f32x4*)(Ak + q * 4);
      f32x4 vv = *(const f32x4*)(vk + q * 4);
      u += aa.x * vv.x + aa.y * vv.y + aa.z * vv.z + aa.w * vv.w;
    }
    pbuf[tid] = u;
  }
  __syncthreads();
  if (tid < 240) {
    int k = tid / 80, i = tid - k * 80;
    uu[k][i] = pbuf[k * 160 + i] + pbuf[k * 160 + 80 + i];
  }
  __syncthreads();

  // ---- Rayleigh via per-wave shuffle butterfly (waves 0..2 = k) ----
  if (tid < 192) {
    int k = tid >> 6, lane = tid & 63;
    float v1 = vbuf[cur][k][lane];
    float u1 = uu[k][lane];
    float a = u1 * v1, b2 = v1 * v1;
    if (lane < 16) {
      float v2 = vbuf[cur][k][64 + lane];
      float u2 = uu[k][64 + lane];
      a += u2 * v2; b2 += v2 * v2;
    }
#pragma unroll
    for (int m = 32; m >= 1; m >>= 1) {
      a += __shfl_xor(a, m);
      b2 += __shfl_xor(b2, m);
    }
    if (lane == 0) lamS[k] = a / b2;
  }
  __syncthreads();
  if (tid == 0) {
    float L0 = -0.1f * lamS[0], L1 = -0.1f * lamS[1], L2 = -0.1f * lamS[2];
    float m = fmaxf(L0, fmaxf(L1, L2));
    float e0 = expf(L0 - m), e1 = expf(L1 - m), e2 = expf(L2 - m);
    float inv = 1.0f / (e0 + e1 + e2);
    wk[0] = e0 * inv; wk[1] = e1 * inv; wk[2] = e2 * inv;
  }
  __syncthreads();

  // ---- tail: (t, d-quad) per thread, all from LDS; short4 stores ----
  {
    const int t = tid >> 6, d0 = (tid & 63) * 4;
    const float w0 = wk[0], w1 = wk[1], w2 = wk[2];
    f32x4 xs = *(const f32x4*)&xsum[t][d0];
    f32x4 c0 = *(const f32x4*)&cent[0][d0];
    f32x4 c1 = *(const f32x4*)&cent[1][d0];
    f32x4 c2 = *(const f32x4*)&cent[2][d0];
    f32x4 go = *(const f32x4*)(graph + (size_t)(b * 8 + t) * 256 + d0);
    size_t rb = ((size_t)(b * 8 + t)) * 1024;
    short4v s0, s1, s2, s3;
#pragma unroll
    for (int q = 0; q < 4; ++q) {
      float xq = xs[q];
      s0[q] = f2bf(fmaxf(w0 * (xq - 10.f * c0[q]), 0.f));
      s1[q] = f2bf(fmaxf(w1 * (xq - 10.f * c1[q]), 0.f));
      s2[q] = f2bf(fmaxf(w2 * (xq - 10.f * c2[q]), 0.f));
      s3[q] = f2bf(fmaxf(go[q], 0.f));
    }
    *(short4v*)&Rbuf[rb + 0 + d0]    = s0;
    *(short4v*)&Rbuf[rb + 256 + d0]  = s1;
    *(short4v*)&Rbuf[rb + 512 + d0]  = s2;
    *(short4v*)&Rbuf[rb + 768 + d0]  = s3;
  }
}

// ---------------------------------------------------------------------------
// Fat prep kernel: blocks [0,5120) transpose W1 slices; [5120,6656) build W2T.
__global__ __launch_bounds__(256) void prep_weights(
    const float* __restrict__ w1_4, const float* __restrict__ w1_3,
    const float* __restrict__ w1_2, const float* __restrict__ w1_1,
    const float* __restrict__ w2a, const float* __restrict__ w2b,
    const float* __restrict__ w2c, const float* __restrict__ w2d,
    short* __restrict__ W1T, short* __restrict__ W2T)
{
  __shared__ float sh[32][33];
  const int blk = blockIdx.x;
  if (blk < 5120) {
    const int slice = blk >> 9, rem = blk & 511;
    const int k0 = (rem & 31) * 32, c0 = (rem >> 5) * 32;
    const float* W1; int j;
    if (slice < 4)      { W1 = w1_4; j = slice; }
    else if (slice < 7) { W1 = w1_3; j = slice - 4; }
    else if (slice < 9) { W1 = w1_2; j = slice - 7; }
    else                { W1 = w1_1; j = 0; }
    const int tx = threadIdx.x & 31, ty = threadIdx.x >> 5;
#pragma unroll
    for (int q = 0; q < 4; ++q) {
      int kk = ty + q * 8;
      sh[kk][tx] = W1[(size_t)(j * 1024 + k0 + kk) * 512 + c0 + tx];
    }
    __syncthreads();
#pragma unroll
    for (int q = 0; q < 4; ++q) {
      int cc = ty + q * 8;
      W1T[(size_t)(slice * 512 + c0 + cc) * 1024 + k0 + tx] = f2bf(sh[tx][cc]);
    }
  } else {
    int idx = (blk - 5120) * 256 + threadIdx.x;    // < 192*2048
    int col = idx >> 11, kg = idx & 2047;
    int si = kg >> 9, kr = kg & 511;
    const float* w = (si == 0) ? w2a : (si == 1) ? w2b : (si == 2) ? w2c : w2d;
    W2T[idx] = (col < 174) ? f2bf(w[(size_t)kr * 174 + col]) : (short)0;
  }
}

// ---------------------------------------------------------------------------
// P(2048 x 5120) bf16 = Rbf(2048x1024) @ W1T^T; 128x128 tile, BK=32, 4 waves.
// Grid (40,16) with bijective XCD-chunked swizzle (B-panel-major).
__global__ __launch_bounds__(256) void p_mfma(
    const short* __restrict__ A, const short* __restrict__ W1T,
    short* __restrict__ P)
{
  __shared__ short As[128 * 32];
  __shared__ short Bs[128 * 32];
  const int id = blockIdx.x + blockIdx.y * 40;     // 640 = 8 XCD * 80
  const int nid = (id & 7) * 80 + (id >> 3);
  const int bx = nid >> 4, by = nid & 15;          // bx 0..39, by 0..15
  const int tid = threadIdx.x, lane = tid & 63, w = tid >> 6;
  const int wr = w >> 1, wc = w & 1;
  const int rowBase = by * 128;
  const short* Bp = W1T + (size_t)bx * 128 * 1024;
  const int rA = w * 16 + (lane >> 2);
  const int kkA = (lane & 3) * 8;

  f32x4 acc[4][4];
#pragma unroll
  for (int m = 0; m < 4; ++m)
#pragma unroll
    for (int n = 0; n < 4; ++n) acc[m][n] = (f32x4){0.f, 0.f, 0.f, 0.f};

  for (int k0 = 0; k0 < 1024; k0 += 32) {
    __syncthreads();
    gload16(A + (size_t)(rowBase + rA) * 1024 + k0 + kkA, As + w * 512);
    gload16(A + (size_t)(rowBase + 64 + rA) * 1024 + k0 + kkA, As + 2048 + w * 512);
    gload16(Bp + (size_t)rA * 1024 + k0 + kkA, Bs + w * 512);
    gload16(Bp + (size_t)(64 + rA) * 1024 + k0 + kkA, Bs + 2048 + w * 512);
    __syncthreads();
    short8v a[4], bv[4];
#pragma unroll
    for (int m = 0; m < 4; ++m)
      a[m] = *(const short8v*)(As + (wr * 64 + m * 16 + (lane & 15)) * 32 + (lane >> 4) * 8);
#pragma unroll
    for (int n = 0; n < 4; ++n)
      bv[n] = *(const short8v*)(Bs + (wc * 64 + n * 16 + (lane & 15)) * 32 + (lane >> 4) * 8);
#pragma unroll
    for (int m = 0; m < 4; ++m)
#pragma unroll
      for (int n = 0; n < 4; ++n)
        acc[m][n] = __builtin_amdgcn_mfma_f32_16x16x32_bf16(a[m], bv[n], acc[m][n], 0, 0, 0);
  }

  const int colG = bx * 128 + wc * 64;
#pragma unroll
  for (int m = 0; m < 4; ++m) {
    int row = rowBase + wr * 64 + m * 16 + (lane >> 4) * 4;
#pragma unroll
    for (int n = 0; n < 4; ++n) {
      int col = colG + n * 16 + (lane & 15);
#pragma unroll
      for (int r = 0; r < 4; ++r)
        P[(size_t)(row + r) * 5120 + col] = f2bf(acc[m][n][r]);
    }
  }
}

// ---------------------------------------------------------------------------
// Hsum[row][si*512+c] bf16; thread owns 2 consecutive cols (short2 loads).
__global__ __launch_bounds__(256) void hsum_all(
    const short* __restrict__ P,
    const float* __restrict__ b1a, const float* __restrict__ b1b,
    const float* __restrict__ b1c, const float* __restrict__ b1d,
    short* __restrict__ Hsum)
{
  const int row = blockIdx.x, t = row & 7, base = row - t;
  const int c0 = threadIdx.x * 2;
  const size_t prow = (size_t)base * 5120;

  {  // si=0, s=4
    float2 bb = *(const float2*)(b1a + c0);
    float a0 = 0.f, a1 = 0.f;
    for (int r = 0; r < 12; ++r) {
      if (ROWS4[r][0] != t) continue;
      float h0 = bb.x, h1 = bb.y;
#pragma unroll
      for (int jj = 0; jj < 4; ++jj) {
        const short2 pv = *(const short2*)(P + prow + (size_t)ROWS4[r][1 + jj] * 5120 + jj * 512 + c0);
        h0 += bf2f(pv.x); h1 += bf2f(pv.y);
      }
      a0 += fmaxf(h0, 0.f); a1 += fmaxf(h1, 0.f);
    }
    uint32_t wv = (uint32_t)(uint16_t)f2bf(a0) | ((uint32_t)(uint16_t)f2bf(a1) << 16);
    *(uint32_t*)&Hsum[(size_t)row * 2048 + c0] = wv;
  }
  {  // si=1, s=3
    float2 bb = *(const float2*)(b1b + c0);
    float a0 = 0.f, a1 = 0.f;
    for (int r = 0; r < 15; ++r) {
      if (ROWS3[r][0] != t) continue;
      float h0 = bb.x, h1 = bb.y;
#pragma unroll
      for (int jj = 0; jj < 3; ++jj) {
        const short2 pv = *(const short2*)(P + prow + (size_t)ROWS3[r][1 + jj] * 5120 + 2048 + jj * 512 + c0);
        h0 += bf2f(pv.x); h1 += bf2f(pv.y);
      }
      a0 += fmaxf(h0, 0.f); a1 += fmaxf(h1, 0.f);
    }
    uint32_t wv = (uint32_t)(uint16_t)f2bf(a0) | ((uint32_t)(uint16_t)f2bf(a1) << 16);
    *(uint32_t*)&Hsum[(size_t)row * 2048 + 512 + c0] = wv;
  }
  {  // si=2, s=2
    float2 bb = *(const float2*)(b1c + c0);
    float a0 = 0.f, a1 = 0.f;
    for (int r = 0; r < 19; ++r) {
      if (ROWS2[r][0] != t) continue;
      float h0 = bb.x, h1 = bb.y;
#pragma unroll
      for (int jj = 0; jj < 2; ++jj) {
        const short2 pv = *(const short2*)(P + prow + (size_t)ROWS2[r][1 + jj] * 5120 + 3584 + jj * 512 + c0);
        h0 += bf2f(pv.x); h1 += bf2f(pv.y);
      }
      a0 += fmaxf(h0, 0.f); a1 += fmaxf(h1, 0.f);
    }
    uint32_t wv = (uint32_t)(uint16_t)f2bf(a0) | ((uint32_t)(uint16_t)f2bf(a1) << 16);
    *(uint32_t*)&Hsum[(size_t)row * 2048 + 1024 + c0] = wv;
  }
  {  // si=3, s=1
    float2 bb = *(const float2*)(b1d + c0);
    float a0 = 0.f, a1 = 0.f;
    for (int r = 0; r < 36; ++r) {
      if (ROWS1[r][0] != t) continue;
      const short2 pv = *(const short2*)(P + prow + (size_t)ROWS1[r][1] * 5120 + 4608 + c0);
      a0 += fmaxf(bb.x + bf2f(pv.x), 0.f);
      a1 += fmaxf(bb.y + bf2f(pv.y), 0.f);
    }
    uint32_t wv = (uint32_t)(uint16_t)f2bf(a0) | ((uint32_t)(uint16_t)f2bf(a1) << 16);
    *(uint32_t*)&Hsum[(size_t)row * 2048 + 1536 + c0] = wv;
  }
}

// ---------------------------------------------------------------------------
// Split-K out GEMM: partial[z][2048][192] = Hsum[:, z*512:(z+1)*512] @ W2T^T.
__global__ __launch_bounds__(256) void out_split(
    const short* __restrict__ H, const short* __restrict__ W2T,
    float* __restrict__ partial)
{
  __shared__ short As[128 * 32];
  __shared__ short Bs[64 * 32];
  const int tid = threadIdx.x, lane = tid & 63, w = tid >> 6;
  const int wr = w >> 1, wc = w & 1;
  const int rowBase = blockIdx.y * 128, colBase = blockIdx.x * 64;
  const int kBase = blockIdx.z * 512;
  const int rA = w * 16 + (lane >> 2);
  const int kkA = (lane & 3) * 8;

  f32x4 acc[4][2];
#pragma unroll
  for (int m = 0; m < 4; ++m)
#pragma unroll
    for (int n = 0; n < 2; ++n) acc[m][n] = (f32x4){0.f, 0.f, 0.f, 0.f};

  for (int k0 = 0; k0 < 512; k0 += 32) {
    const int kg = kBase + k0;
    __syncthreads();
    gload16(H + (size_t)(rowBase + rA) * 2048 + kg + kkA, As + w * 512);
    gload16(H + (size_t)(rowBase + 64 + rA) * 2048 + kg + kkA, As + 2048 + w * 512);
    gload16(W2T + (size_t)(colBase + rA) * 2048 + kg + kkA, Bs + w * 512);
    __syncthreads();
    short8v a[4], bv[2];
#pragma unroll
    for (int m = 0; m < 4; ++m)
      a[m] = *(const short8v*)(As + (wr * 64 + m * 16 + (lane & 15)) * 32 + (lane >> 4) * 8);
#pragma unroll
    for (int n = 0; n < 2; ++n)
      bv[n] = *(const short8v*)(Bs + (wc * 32 + n * 16 + (lane & 15)) * 32 + (lane >> 4) * 8);
#pragma unroll
    for (int m = 0; m < 4; ++m)
#pragma unroll
      for (int n = 0; n < 2; ++n)
        acc[m][n] = __builtin_amdgcn_mfma_f32_16x16x32_bf16(a[m], bv[n], acc[m][n], 0, 0, 0);
  }

  float* pz = partial + (size_t)blockIdx.z * 2048 * 192;
#pragma unroll
  for (int n = 0; n < 2; ++n) {
    int col = colBase + wc * 32 + n * 16 + (lane & 15);
#pragma unroll
    for (int m = 0; m < 4; ++m) {
      int row0 = rowBase + wr * 64 + m * 16 + (lane >> 4) * 4;
#pragma unroll
      for (int r = 0; r < 4; ++r)
        pz[(size_t)(row0 + r) * 192 + col] = acc[m][n][r];
    }
  }
}

// ---------------------------------------------------------------------------
__global__ __launch_bounds__(256) void out_reduce(
    const float* __restrict__ partial,
    const float* __restrict__ b2a, const float* __restrict__ b2b,
    const float* __restrict__ b2c, const float* __restrict__ b2d,
    float* __restrict__ out)
{
  const int row = blockIdx.x, col = threadIdx.x;
  if (col >= 174) return;
  const size_t o = (size_t)row * 192 + col;
  float s = partial[o] + partial[o + (size_t)2048 * 192]
          + partial[o + (size_t)4096 * 192] + partial[o + (size_t)6144 * 192];
  int tt = row & 7;
  float bias = CNT[tt][0] * b2a[col] + CNT[tt][1] * b2b[col]
             + CNT[tt][2] * b2c[col] + CNT[tt][3] * b2d[col];
  out[(size_t)row * 174 + col] = s + bias;
}

// ---------------------------------------------------------------------------
extern "C" void kernel_launch(void* const* d_in, const int* in_sizes, int n_in,
                              void* d_out, int out_size, void* d_ws, size_t ws_size,
                              hipStream_t stream) {
  const float* graph = (const float*)d_in[0];
  const float* init  = (const float*)d_in[1];
  const float* w1[4] = {(const float*)d_in[3],  (const float*)d_in[7],
                        (const float*)d_in[11], (const float*)d_in[15]};
  const float* b1[4] = {(const float*)d_in[4],  (const float*)d_in[8],
                        (const float*)d_in[12], (const float*)d_in[16]};
  const float* w2[4] = {(const float*)d_in[5],  (const float*)d_in[9],
                        (const float*)d_in[13], (const float*)d_in[17]};
  const float* b2[4] = {(const float*)d_in[6],  (const float*)d_in[10],
                        (const float*)d_in[14], (const float*)d_in[18]};
  float* out = (float*)d_out;

  char* ws = (char*)d_ws;
  short* Rbf  = (short*)(ws + 0);                    // 4 MiB   (dead after p_mfma)
  short* W1T  = (short*)(ws + ((size_t)4  << 20));   // 10 MiB  (dead after p_mfma)
  short* P    = (short*)(ws + ((size_t)14 << 20));   // 20 MiB  (dead after hsum_all)
  short* W2T  = (short*)(ws + ((size_t)34 << 20));   // 0.75 MiB
  short* Hsum = (short*)(ws + 0);                    // 8 MiB   (over Rbf/W1T head)
  float* Part = (float*)(ws + ((size_t)8 << 20));    // 6.29 MiB (over W1T tail/P head)

  var_kernel<<<256, 512, 0, stream>>>(init, graph, Rbf);

  prep_weights<<<6656, 256, 0, stream>>>(w1[0], w1[1], w1[2], w1[3],
                                         w2[0], w2[1], w2[2], w2[3], W1T, W2T);

  p_mfma<<<dim3(40, 16), 256, 0, stream>>>(Rbf, W1T, P);

  hsum_all<<<2048, 256, 0, stream>>>(P, b1[0], b1[1], b1[2], b1[3], Hsum);

  out_split<<<dim3(3, 16, 4), 256, 0, stream>>>(Hsum, W2T, Part);

  out_reduce<<<2048, 256, 0, stream>>>(Part, b2[0], b2[1], b2[2], b2[3], out);
}